// Round 6
// baseline (166.319 us; speedup 1.0000x reference)
//
#include <hip/hip_runtime.h>

typedef unsigned short u16;
typedef __attribute__((ext_vector_type(8))) short short8;
typedef __attribute__((ext_vector_type(4))) float f32x4;
typedef __attribute__((ext_vector_type(16))) float f32x16;

#define DEV __device__ __forceinline__

static constexpr int BATCH   = 16384;
static constexpr int NTAB    = 26;
static constexpr int VOCAB   = 100000;
static constexpr int DIM     = 64;

DEV u16 f2bf(float f){
  union { float f; unsigned u; } x; x.f = f;
  unsigned r = x.u + 0x7fffu + ((x.u >> 16) & 1u);
  return (u16)(r >> 16);
}
DEV float bf2f(u16 h){
  union { unsigned u; float f; } x; x.u = ((unsigned)h) << 16;
  return x.f;
}

// async global->LDS, 16B per lane. dst must be the wave-uniform base; HW adds lane*16.
DEV void llds16(u16* dst, const u16* src){
  __builtin_amdgcn_global_load_lds(
      (const __attribute__((address_space(1))) unsigned*)src,
      (__attribute__((address_space(3))) unsigned*)dst, 16, 0, 0);
}

// ---------------- prep: dense xsplit + tiled weight transpose/split ---------------
// Weight tiles: src[K][N] f32 -> dst[N][2*Kpad] bf16 compact [Bh | Bl], via 32x32
// LDS tile so global reads are coalesced f32 and writes are 64B u16 runs.
DEV void wtile(const float* __restrict__ src, u16* __restrict__ dst,
               int K, int N, int Kpad, int tile)
{
  __shared__ float ld[32][33];
  const int nt = N >> 5;
  const int k0 = (tile / nt) << 5;
  const int n0 = (tile % nt) << 5;
  const int tx = threadIdx.x & 31;   // fast dim
  const int ty = threadIdx.x >> 5;   // 8 rows per pass
  #pragma unroll
  for (int it = 0; it < 4; ++it) {
    int k = k0 + ty + 8 * it;
    ld[ty + 8 * it][tx] = (k < K) ? src[(size_t)k * N + n0 + tx] : 0.f;
  }
  __syncthreads();
  #pragma unroll
  for (int it = 0; it < 4; ++it) {
    int n  = n0 + ty + 8 * it;
    int kp = k0 + tx;
    float v = ld[tx][ty + 8 * it];
    u16 hi = f2bf(v);
    u16 lo = f2bf(v - bf2f(hi));
    u16* p = dst + (size_t)n * 2 * Kpad;
    p[kp] = hi; p[Kpad + kp] = lo;
  }
}

__global__ void prep_k(const float* __restrict__ dense, u16* __restrict__ Xs,
                       const float* __restrict__ bw1, u16* __restrict__ W1s,
                       const float* __restrict__ bw2, u16* __restrict__ W2s,
                       const float* __restrict__ bw3, u16* __restrict__ W3s,
                       const float* __restrict__ tw1, u16* __restrict__ WT1s,
                       const float* __restrict__ tw2, u16* __restrict__ WT2s)
{
  int blk = blockIdx.x;
  if (blk < 2048) {                       // dense: [B][13] -> [B][64] = [Ah(32)|Al(32)]
    int i = blk * 256 + threadIdx.x;      // B*32 items
    int b = i >> 5, k = i & 31;
    float v = (k < 13) ? dense[b * 13 + k] : 0.f;
    u16 hi = f2bf(v);
    u16 lo = f2bf(v - bf2f(hi));
    u16* p = Xs + (size_t)b * 64;
    p[k] = hi; p[32 + k] = lo;
  }
  else if (blk < 2064) wtile(bw1, W1s, 13, 512, 32,   blk - 2048);  // 1x16
  else if (blk < 2192) wtile(bw2, W2s, 512, 256, 512, blk - 2064);  // 16x8
  else if (blk < 2208) wtile(bw3, W3s, 256, 64, 256,  blk - 2192);  // 8x2
  else if (blk < 2432) wtile(tw1, WT1s, 442, 512, 448, blk - 2208); // 14x16
  else                 wtile(tw2, WT2s, 512, 256, 512, blk - 2432); // 16x8
}

// ---------------- GEMM: C[M][N] = relu(A * B^T + bias), split-fp32 emulation ------
// A stored [M][2*Khalf] = [Ah|Al]; Bt stored [N][2*Khalf] = [Bh|Bl].
// A (real 2x cross-wave reuse + coalescing) staged via global_load_lds, XOR-swizzled.
// B (zero cross-wave reuse, L2-resident weights) loaded DIRECTLY global->VGPR
// [mistake #7: no-reuse LDS staging is pure overhead]. LDS = A only (32KB at 128-tile)
// -> higher blocks/CU, half the ds_reads, vmcnt drain waits on 8 loads not 16.
// 32x32x16 bf16 MFMA; 3 combos (hi.hi + hi.lo + lo.hi) per staged A tile-set.
// OUTMODE 0: compact split bf16 [M][2*ldc]=[Ch|Cl]. OUTMODE 1: fp32 [M][ldc].
// OUTMODE 2: fused last layer: part[(n0/BN)*BATCH + row] = sum_col relu(y)*w3[col].
template<int BM, int BN, int BK, int WM, int WN, int OUTMODE>
__global__ __launch_bounds__(WM * WN * 64)
void gemm_bt(const u16* __restrict__ A, const u16* __restrict__ Bt,
             const float* __restrict__ bias, void* __restrict__ Cout,
             int Khalf, int nbn, int lda, int ldb, int ldc,
             const float* __restrict__ w3, float* __restrict__ part)
{
  constexpr int THREADS = WM * WN * 64;
  constexpr int ROWB    = BK * 2;        // bytes per LDS row
  constexpr int SW      = ROWB / 16 - 1; // swizzle mask over 16B slots
  constexpr int AIT     = (BM * ROWB) / (THREADS * 16);

  __shared__ alignas(16) u16 Asm[2][BM * BK];  // [hi|lo], A only

  const int tid  = threadIdx.x;
  const int lane = tid & 63;
  const int wid  = tid >> 6;
  const int wm   = wid / WN;
  const int wn   = wid % WN;

  // T1: XCD-aware bijective chunk swizzle (all our grids are %8 == 0)
  int bid = blockIdx.x;
  {
    int nwg = gridDim.x;
    if ((nwg & 7) == 0) { int q = nwg >> 3; bid = (bid & 7) * q + (bid >> 3); }
  }
  const int m0   = (bid / nbn) * BM;
  const int n0   = (bid % nbn) * BN;
  const int l31  = lane & 31;
  const int half = lane >> 5;

  f32x16 acc[2][2] = {};

  // per-lane B row base (rows are private to the lane; no LDS staging)
  const u16* browp[2];
  #pragma unroll
  for (int ni = 0; ni < 2; ++ni)
    browp[ni] = Bt + (size_t)(n0 + wn * 64 + ni * 32 + l31) * ldb;

  for (int k0 = 0; k0 < Khalf; k0 += BK) {
    #pragma unroll
    for (int h = 0; h < 2; ++h) {
      const int koff = k0 + h * Khalf;   // hi section at k0, lo at Khalf+k0
      #pragma unroll
      for (int it = 0; it < AIT; ++it) {
        int loff = (it * THREADS + tid) * 16;
        int row  = loff / ROWB;
        int slot = (loff % ROWB) >> 4;
        int gs   = slot ^ (row & SW);
        llds16(Asm[h] + (size_t)(it * THREADS + (wid << 6)) * 8,
               A + (size_t)(m0 + row) * lda + koff + gs * 8);
      }
    }
    asm volatile("s_waitcnt vmcnt(0)" ::: "memory");
    __syncthreads();

    #pragma unroll
    for (int ks = 0; ks < BK / 16; ++ks) {
      short8 ah[2], al[2], bh[2], bl[2];
      #pragma unroll
      for (int mi = 0; mi < 2; ++mi) {
        int row = wm * 64 + mi * 32 + l31;
        int sl  = (2 * ks + half) ^ (row & SW);
        ah[mi] = *(const short8*)(Asm[0] + (size_t)row * BK + sl * 8);
        al[mi] = *(const short8*)(Asm[1] + (size_t)row * BK + sl * 8);
      }
      #pragma unroll
      for (int ni = 0; ni < 2; ++ni) {
        const u16* bp = browp[ni] + k0 + (2 * ks + half) * 8;
        bh[ni] = *(const short8*)(bp);          // hi section
        bl[ni] = *(const short8*)(bp + Khalf);  // lo section
      }
      #pragma unroll
      for (int mi = 0; mi < 2; ++mi)
        #pragma unroll
        for (int ni = 0; ni < 2; ++ni)
          acc[mi][ni] = __builtin_amdgcn_mfma_f32_32x32x16_bf16(
              ah[mi], bh[ni], acc[mi][ni], 0, 0, 0);
      #pragma unroll
      for (int mi = 0; mi < 2; ++mi)
        #pragma unroll
        for (int ni = 0; ni < 2; ++ni)
          acc[mi][ni] = __builtin_amdgcn_mfma_f32_32x32x16_bf16(
              ah[mi], bl[ni], acc[mi][ni], 0, 0, 0);
      #pragma unroll
      for (int mi = 0; mi < 2; ++mi)
        #pragma unroll
        for (int ni = 0; ni < 2; ++ni)
          acc[mi][ni] = __builtin_amdgcn_mfma_f32_32x32x16_bf16(
              al[mi], bh[ni], acc[mi][ni], 0, 0, 0);
    }
    __syncthreads();
  }

  // epilogue. 32x32 C/D map: col = lane&31, row = (reg&3)+8*(reg>>2)+4*(lane>>5) [m74/m101]
  if constexpr (OUTMODE == 2) {
    // fused final layer: per-row partial dot of relu(y + bias) with w3
    __shared__ float redbuf[WN][BM];
    #pragma unroll
    for (int mi = 0; mi < 2; ++mi) {
      #pragma unroll
      for (int reg = 0; reg < 16; ++reg) {
        float s = 0.f;
        #pragma unroll
        for (int ni = 0; ni < 2; ++ni) {
          int col = n0 + wn * 64 + ni * 32 + l31;
          s += fmaxf(acc[mi][ni][reg] + bias[col], 0.f) * w3[col];
        }
        #pragma unroll
        for (int off = 16; off; off >>= 1) s += __shfl_xor(s, off);
        if (l31 == 0)
          redbuf[wn][wm * 64 + mi * 32 + (reg & 3) + 8 * (reg >> 2) + 4 * half] = s;
      }
    }
    __syncthreads();
    if (tid < BM) {
      float s = redbuf[0][tid];
      #pragma unroll
      for (int w = 1; w < WN; ++w) s += redbuf[w][tid];
      part[(size_t)(n0 / BN) * BATCH + m0 + tid] = s;
    }
  } else {
    #pragma unroll
    for (int ni = 0; ni < 2; ++ni) {
      int col  = n0 + wn * 64 + ni * 32 + l31;
      float bv = bias[col];
      #pragma unroll
      for (int mi = 0; mi < 2; ++mi) {
        #pragma unroll
        for (int reg = 0; reg < 16; ++reg) {
          int rowm = m0 + wm * 64 + mi * 32 + (reg & 3) + 8 * (reg >> 2) + 4 * half;
          float v  = fmaxf(acc[mi][ni][reg] + bv, 0.f);
          if (OUTMODE == 1) {
            ((float*)Cout)[(size_t)rowm * ldc + col] = v;
          } else {
            u16 hi = f2bf(v);
            u16 lo = f2bf(v - bf2f(hi));
            u16* p = (u16*)Cout + (size_t)rowm * 2 * ldc;
            p[col] = hi; p[ldc + col] = lo;
          }
        }
      }
    }
  }
}

// ---------------- interaction: gather + Z = T*T^T (triu), compact split out -------
// One wave per batch row. T = [dx; 26 embedding rows] (27x64, rows padded to 32).
// Split Gram: Z ~ Th.Th^T + Th.Tl^T + Tl.Th^T via 3 MFMAs per k-slice.
// Output: Is[b][896] = [Ih(448) | Il(448)], I = [dx(64), triu(378), 0pad(6)]
__global__ __launch_bounds__(256)
void interact_k(const float* __restrict__ dxf, const int* __restrict__ sidx,
                const float* __restrict__ tables, u16* __restrict__ Is)
{
  const int lane = threadIdx.x & 63;
  const int b    = blockIdx.x * 4 + (threadIdx.x >> 6);
  const float* dxrow = dxf + (size_t)b * DIM;
  u16* irow = Is + (size_t)b * 896;

  // dense part, cols [0,64)
  {
    float v  = dxrow[lane];
    u16 hi = f2bf(v);
    u16 lo = f2bf(v - bf2f(hi));
    irow[lane] = hi; irow[448 + lane] = lo;
  }
  if (lane < 6) { irow[442 + lane] = 0; irow[448 + 442 + lane] = 0; }

  const int r    = lane & 31;
  const int half = lane >> 5;
  const float* src = nullptr;
  if (r == 0)       src = dxrow;
  else if (r <= 26) {
    int id = sidx[b * NTAB + (r - 1)];
    src = tables + ((size_t)(r - 1) * VOCAB + (size_t)id) * DIM;
  }

  short8 fh[4], fl[4];
  #pragma unroll
  for (int ks = 0; ks < 4; ++ks) {
    short8 h = {}, l = {};
    if (src) {
      const float* p = src + ks * 16 + half * 8;
      f32x4 a = *(const f32x4*)(p);
      f32x4 c = *(const f32x4*)(p + 4);
      #pragma unroll
      for (int j = 0; j < 4; ++j) {
        u16 ha = f2bf(a[j]); h[j]     = (short)ha; l[j]     = (short)f2bf(a[j] - bf2f(ha));
        u16 hc = f2bf(c[j]); h[j + 4] = (short)hc; l[j + 4] = (short)f2bf(c[j] - bf2f(hc));
      }
    }
    fh[ks] = h; fl[ks] = l;
  }

  f32x16 z = {};
  #pragma unroll
  for (int ks = 0; ks < 4; ++ks) {
    z = __builtin_amdgcn_mfma_f32_32x32x16_bf16(fh[ks], fh[ks], z, 0, 0, 0);
    z = __builtin_amdgcn_mfma_f32_32x32x16_bf16(fh[ks], fl[ks], z, 0, 0, 0);
    z = __builtin_amdgcn_mfma_f32_32x32x16_bf16(fl[ks], fh[ks], z, 0, 0, 0);
  }

  const int col = r;
  if (col < 27) {
    #pragma unroll
    for (int reg = 0; reg < 16; ++reg) {
      int rw = (reg & 3) + 8 * (reg >> 2) + 4 * half;
      if (rw <= col) {
        int flat = rw * 27 - rw * (rw - 1) / 2 + (col - rw);
        float v  = z[reg];
        u16 hi = f2bf(v);
        u16 lo = f2bf(v - bf2f(hi));
        irow[64 + flat] = hi; irow[448 + 64 + flat] = lo;
      }
    }
  }
}

// ---------------- finisher: out[b] = sigmoid(part0[b] + part1[b] + b3) ------------
__global__ __launch_bounds__(256)
void final2_k(const float* __restrict__ part, const float* __restrict__ b3,
              float* __restrict__ out)
{
  int i = blockIdx.x * 256 + threadIdx.x;
  float s = part[i] + part[BATCH + i] + b3[0];
  out[i] = 1.f / (1.f + expf(-s));
}

// ----------------------------------------------------------------------------------
extern "C" void kernel_launch(void* const* d_in, const int* in_sizes, int n_in,
                              void* d_out, int out_size, void* d_ws, size_t ws_size,
                              hipStream_t stream)
{
  const float* dense  = (const float*)d_in[0];
  const int*   sidx   = (const int*)d_in[1];
  const float* tables = (const float*)d_in[2];
  const float* bw1 = (const float*)d_in[3];  const float* bb1 = (const float*)d_in[4];
  const float* bw2 = (const float*)d_in[5];  const float* bb2 = (const float*)d_in[6];
  const float* bw3 = (const float*)d_in[7];  const float* bb3 = (const float*)d_in[8];
  const float* tw1 = (const float*)d_in[9];  const float* tb1 = (const float*)d_in[10];
  const float* tw2 = (const float*)d_in[11]; const float* tb2 = (const float*)d_in[12];
  const float* tw3 = (const float*)d_in[13]; const float* tb3 = (const float*)d_in[14];
  float* out = (float*)d_out;

  char* ws = (char*)d_ws;
  size_t off = 0;
  auto alloc = [&](size_t bytes) { size_t o = off; off += (bytes + 1023) & ~(size_t)1023; return o; };

  u16*  Xs   = (u16*)(ws + alloc((size_t)BATCH * 64 * 2));    // [B][2*32]
  u16*  W1s  = (u16*)(ws + alloc((size_t)512 * 64 * 2));      // [512][2*32]
  u16*  W2s  = (u16*)(ws + alloc((size_t)256 * 1024 * 2));    // [256][2*512]
  u16*  W3s  = (u16*)(ws + alloc((size_t)64 * 512 * 2));      // [64][2*256]
  u16*  WT1s = (u16*)(ws + alloc((size_t)512 * 896 * 2));     // [512][2*448]
  u16*  WT2s = (u16*)(ws + alloc((size_t)256 * 1024 * 2));    // [256][2*512]
  u16*  A1s  = (u16*)(ws + alloc((size_t)BATCH * 1024 * 2));  // [B][2*512] (reused as B1s)
  u16*  A2s  = (u16*)(ws + alloc((size_t)BATCH * 512 * 2));   // [B][2*256]
  float* dxf = (float*)(ws + alloc((size_t)BATCH * 64 * 4));  // [B][64] fp32
  u16*  Is   = (u16*)(ws + alloc((size_t)BATCH * 896 * 2));   // [B][2*448]
  float* part= (float*)(ws + alloc((size_t)2 * BATCH * 4));   // [2][B] fused-dot partials
  u16*  B1s  = A1s;  // A1s dead after bottom GEMM2; reuse for top-MLP hidden
  (void)ws_size; (void)n_in; (void)in_sizes; (void)out_size;

  // merged input conversion + tiled weight transpose/split (one launch)
  prep_k<<<2560, 256, 0, stream>>>(dense, Xs, bw1, W1s, bw2, W2s, bw3, W3s,
                                   tw1, WT1s, tw2, WT2s);

  // bottom MLP (A staged in LDS; B direct from L2)
  gemm_bt<128, 128, 32, 2, 2, 0><<<(BATCH / 128) * (512 / 128), 256, 0, stream>>>(
      Xs, W1s, bb1, A1s, 32, 512 / 128, 64, 64, 512, nullptr, nullptr);
  gemm_bt<128, 128, 64, 2, 2, 0><<<(BATCH / 128) * (256 / 128), 256, 0, stream>>>(
      A1s, W2s, bb2, A2s, 512, 256 / 128, 1024, 1024, 256, nullptr, nullptr);
  gemm_bt<64, 64, 64, 1, 1, 1><<<(BATCH / 64) * (64 / 64), 64, 0, stream>>>(
      A2s, W3s, bb3, dxf, 256, 64 / 64, 512, 512, 64, nullptr, nullptr);

  // gather + pairwise interaction (compact split output)
  interact_k<<<BATCH / 4, 256, 0, stream>>>(dxf, sidx, tables, Is);

  // top MLP (layer 3 fused into layer-2 epilogue as partial dots)
  gemm_bt<128, 128, 64, 2, 2, 0><<<(BATCH / 128) * (512 / 128), 256, 0, stream>>>(
      Is, WT1s, tb1, B1s, 448, 512 / 128, 896, 896, 512, nullptr, nullptr);
  gemm_bt<128, 128, 64, 2, 2, 2><<<(BATCH / 128) * (256 / 128), 256, 0, stream>>>(
      B1s, WT2s, tb2, nullptr, 512, 256 / 128, 1024, 1024, 256, tw3, part);
  final2_k<<<BATCH / 256, 256, 0, stream>>>(part, tb3, out);
}

// Round 7
// 140.348 us; speedup vs baseline: 1.1851x; 1.1851x over previous
//
#include <hip/hip_runtime.h>

typedef unsigned short u16;
typedef __attribute__((ext_vector_type(8))) short short8;
typedef __attribute__((ext_vector_type(4))) float f32x4;
typedef __attribute__((ext_vector_type(16))) float f32x16;

#define DEV __device__ __forceinline__

static constexpr int BATCH   = 16384;
static constexpr int NTAB    = 26;
static constexpr int VOCAB   = 100000;
static constexpr int DIM     = 64;

DEV u16 f2bf(float f){
  union { float f; unsigned u; } x; x.f = f;
  unsigned r = x.u + 0x7fffu + ((x.u >> 16) & 1u);
  return (u16)(r >> 16);
}
DEV float bf2f(u16 h){
  union { unsigned u; float f; } x; x.u = ((unsigned)h) << 16;
  return x.f;
}

// async global->LDS, 16B per lane. dst must be the wave-uniform base; HW adds lane*16.
DEV void llds16(u16* dst, const u16* src){
  __builtin_amdgcn_global_load_lds(
      (const __attribute__((address_space(1))) unsigned*)src,
      (__attribute__((address_space(3))) unsigned*)dst, 16, 0, 0);
}

// ---------------- prep: dense xsplit + tiled weight transpose/split ---------------
// Weight tiles: src[K][N] f32 -> dst[N][2*Kpad] bf16 compact [Bh | Bl], via 32x32
// LDS tile so global reads are coalesced f32 and writes are 64B u16 runs.
DEV void wtile(const float* __restrict__ src, u16* __restrict__ dst,
               int K, int N, int Kpad, int tile)
{
  __shared__ float ld[32][33];
  const int nt = N >> 5;
  const int k0 = (tile / nt) << 5;
  const int n0 = (tile % nt) << 5;
  const int tx = threadIdx.x & 31;   // fast dim
  const int ty = threadIdx.x >> 5;   // 8 rows per pass
  #pragma unroll
  for (int it = 0; it < 4; ++it) {
    int k = k0 + ty + 8 * it;
    ld[ty + 8 * it][tx] = (k < K) ? src[(size_t)k * N + n0 + tx] : 0.f;
  }
  __syncthreads();
  #pragma unroll
  for (int it = 0; it < 4; ++it) {
    int n  = n0 + ty + 8 * it;
    int kp = k0 + tx;
    float v = ld[tx][ty + 8 * it];
    u16 hi = f2bf(v);
    u16 lo = f2bf(v - bf2f(hi));
    u16* p = dst + (size_t)n * 2 * Kpad;
    p[kp] = hi; p[Kpad + kp] = lo;
  }
}

__global__ void prep_k(const float* __restrict__ dense, u16* __restrict__ Xs,
                       const float* __restrict__ bw1, u16* __restrict__ W1s,
                       const float* __restrict__ bw2, u16* __restrict__ W2s,
                       const float* __restrict__ bw3, u16* __restrict__ W3s,
                       const float* __restrict__ tw1, u16* __restrict__ WT1s,
                       const float* __restrict__ tw2, u16* __restrict__ WT2s)
{
  int blk = blockIdx.x;
  if (blk < 2048) {                       // dense: [B][13] -> [B][64] = [Ah(32)|Al(32)]
    int i = blk * 256 + threadIdx.x;      // B*32 items
    int b = i >> 5, k = i & 31;
    float v = (k < 13) ? dense[b * 13 + k] : 0.f;
    u16 hi = f2bf(v);
    u16 lo = f2bf(v - bf2f(hi));
    u16* p = Xs + (size_t)b * 64;
    p[k] = hi; p[32 + k] = lo;
  }
  else if (blk < 2064) wtile(bw1, W1s, 13, 512, 32,   blk - 2048);  // 1x16
  else if (blk < 2192) wtile(bw2, W2s, 512, 256, 512, blk - 2064);  // 16x8
  else if (blk < 2208) wtile(bw3, W3s, 256, 64, 256,  blk - 2192);  // 8x2
  else if (blk < 2432) wtile(tw1, WT1s, 442, 512, 448, blk - 2208); // 14x16
  else                 wtile(tw2, WT2s, 512, 256, 512, blk - 2432); // 16x8
}

// ---------------- GEMM: C[M][N] = relu(A * B^T + bias), split-fp32 emulation ------
// A stored [M][2*Khalf] = [Ah|Al]; Bt stored [N][2*Khalf] = [Bh|Bl].
// Per K-step stage 4 tiles (A-hi/lo, B-hi/lo); run 3 combos (hi.hi+hi.lo+lo.hi).
// DOUBLE-BUFFERED prefetch (T3-min): issue next step's global_load_lds right after
// the barrier so DMA lands during current compute; vmcnt(0) at loop head is ~free.
// 32x32x16 bf16 MFMA, wave tile 64x64 = 2x2 frags, XOR-swizzled LDS.
// OUTMODE 0: compact split bf16 [M][2*ldc]=[Ch|Cl]. OUTMODE 1: fp32 [M][ldc].
// OUTMODE 2: fused last layer: part[(n0/BN)*BATCH + row] = sum_col relu(y)*w3[col].
template<int BM, int BN, int BK, int WM, int WN, int OUTMODE>
__global__ __launch_bounds__(WM * WN * 64)
void gemm_bt(const u16* __restrict__ A, const u16* __restrict__ Bt,
             const float* __restrict__ bias, void* __restrict__ Cout,
             int Khalf, int nbn, int lda, int ldb, int ldc,
             const float* __restrict__ w3, float* __restrict__ part)
{
  constexpr int THREADS = WM * WN * 64;
  constexpr int ROWB    = BK * 2;        // bytes per LDS row
  constexpr int SW      = ROWB / 16 - 1; // swizzle mask over 16B slots
  constexpr int AIT     = (BM * ROWB) / (THREADS * 16);
  constexpr int BIT     = (BN * ROWB) / (THREADS * 16);

  __shared__ alignas(16) u16 Asm[2][2][BM * BK];  // [buf][hi|lo]
  __shared__ alignas(16) u16 Bsm[2][2][BN * BK];  // [buf][hi|lo]

  const int tid  = threadIdx.x;
  const int lane = tid & 63;
  const int wid  = tid >> 6;
  const int wm   = wid / WN;
  const int wn   = wid % WN;

  // T1: XCD-aware bijective chunk swizzle (all our grids are %8 == 0)
  int bid = blockIdx.x;
  {
    int nwg = gridDim.x;
    if ((nwg & 7) == 0) { int q = nwg >> 3; bid = (bid & 7) * q + (bid >> 3); }
  }
  const int m0   = (bid / nbn) * BM;
  const int n0   = (bid % nbn) * BN;
  const int l31  = lane & 31;
  const int half = lane >> 5;

  f32x16 acc[2][2] = {};

  auto stage = [&](int t, int buf) {
    const int k0s = t * BK;
    #pragma unroll
    for (int h = 0; h < 2; ++h) {
      const int koff = k0s + h * Khalf;   // hi section at k0, lo at Khalf+k0
      #pragma unroll
      for (int it = 0; it < AIT; ++it) {
        int loff = (it * THREADS + tid) * 16;
        int row  = loff / ROWB;
        int slot = (loff % ROWB) >> 4;
        int gs   = slot ^ (row & SW);
        llds16(&Asm[buf][h][(size_t)(it * THREADS + (wid << 6)) * 8],
               A + (size_t)(m0 + row) * lda + koff + gs * 8);
      }
      #pragma unroll
      for (int it = 0; it < BIT; ++it) {
        int loff = (it * THREADS + tid) * 16;
        int row  = loff / ROWB;
        int slot = (loff % ROWB) >> 4;
        int gs   = slot ^ (row & SW);
        llds16(&Bsm[buf][h][(size_t)(it * THREADS + (wid << 6)) * 8],
               Bt + (size_t)(n0 + row) * ldb + koff + gs * 8);
      }
    }
  };

  const int nsteps = Khalf / BK;
  stage(0, 0);                       // prologue
  int cur = 0;

  for (int t = 0; t < nsteps; ++t) {
    asm volatile("s_waitcnt vmcnt(0)" ::: "memory");
    __syncthreads();                 // buf[cur] fully landed for all waves
    if (t + 1 < nsteps) stage(t + 1, cur ^ 1);  // DMA flies under compute

    #pragma unroll
    for (int ks = 0; ks < BK / 16; ++ks) {
      short8 ah[2], al[2], bh[2], bl[2];
      #pragma unroll
      for (int mi = 0; mi < 2; ++mi) {
        int row = wm * 64 + mi * 32 + l31;
        int sl  = (2 * ks + half) ^ (row & SW);
        ah[mi] = *(const short8*)(&Asm[cur][0][(size_t)row * BK + sl * 8]);
        al[mi] = *(const short8*)(&Asm[cur][1][(size_t)row * BK + sl * 8]);
      }
      #pragma unroll
      for (int ni = 0; ni < 2; ++ni) {
        int row = wn * 64 + ni * 32 + l31;
        int sl  = (2 * ks + half) ^ (row & SW);
        bh[ni] = *(const short8*)(&Bsm[cur][0][(size_t)row * BK + sl * 8]);
        bl[ni] = *(const short8*)(&Bsm[cur][1][(size_t)row * BK + sl * 8]);
      }
      #pragma unroll
      for (int mi = 0; mi < 2; ++mi)
        #pragma unroll
        for (int ni = 0; ni < 2; ++ni)
          acc[mi][ni] = __builtin_amdgcn_mfma_f32_32x32x16_bf16(
              ah[mi], bh[ni], acc[mi][ni], 0, 0, 0);
      #pragma unroll
      for (int mi = 0; mi < 2; ++mi)
        #pragma unroll
        for (int ni = 0; ni < 2; ++ni)
          acc[mi][ni] = __builtin_amdgcn_mfma_f32_32x32x16_bf16(
              ah[mi], bl[ni], acc[mi][ni], 0, 0, 0);
      #pragma unroll
      for (int mi = 0; mi < 2; ++mi)
        #pragma unroll
        for (int ni = 0; ni < 2; ++ni)
          acc[mi][ni] = __builtin_amdgcn_mfma_f32_32x32x16_bf16(
              al[mi], bh[ni], acc[mi][ni], 0, 0, 0);
    }
    __syncthreads();                 // reads of buf[cur] done before it's re-staged
    cur ^= 1;
  }

  // epilogue. 32x32 C/D map: col = lane&31, row = (reg&3)+8*(reg>>2)+4*(lane>>5) [m74/m101]
  if constexpr (OUTMODE == 2) {
    // fused final layer: per-row partial dot of relu(y + bias) with w3
    __shared__ float redbuf[WN][BM];
    #pragma unroll
    for (int mi = 0; mi < 2; ++mi) {
      #pragma unroll
      for (int reg = 0; reg < 16; ++reg) {
        float s = 0.f;
        #pragma unroll
        for (int ni = 0; ni < 2; ++ni) {
          int col = n0 + wn * 64 + ni * 32 + l31;
          s += fmaxf(acc[mi][ni][reg] + bias[col], 0.f) * w3[col];
        }
        #pragma unroll
        for (int off = 16; off; off >>= 1) s += __shfl_xor(s, off);
        if (l31 == 0)
          redbuf[wn][wm * 64 + mi * 32 + (reg & 3) + 8 * (reg >> 2) + 4 * half] = s;
      }
    }
    __syncthreads();
    if (tid < BM) {
      float s = redbuf[0][tid];
      #pragma unroll
      for (int w = 1; w < WN; ++w) s += redbuf[w][tid];
      part[(size_t)(n0 / BN) * BATCH + m0 + tid] = s;
    }
  } else {
    #pragma unroll
    for (int ni = 0; ni < 2; ++ni) {
      int col  = n0 + wn * 64 + ni * 32 + l31;
      float bv = bias[col];
      #pragma unroll
      for (int mi = 0; mi < 2; ++mi) {
        #pragma unroll
        for (int reg = 0; reg < 16; ++reg) {
          int rowm = m0 + wm * 64 + mi * 32 + (reg & 3) + 8 * (reg >> 2) + 4 * half;
          float v  = fmaxf(acc[mi][ni][reg] + bv, 0.f);
          if (OUTMODE == 1) {
            ((float*)Cout)[(size_t)rowm * ldc + col] = v;
          } else {
            u16 hi = f2bf(v);
            u16 lo = f2bf(v - bf2f(hi));
            u16* p = (u16*)Cout + (size_t)rowm * 2 * ldc;
            p[col] = hi; p[ldc + col] = lo;
          }
        }
      }
    }
  }
}

// ---------------- interaction: gather + Z = T*T^T (triu), compact split out -------
// One wave per batch row. T = [dx; 26 embedding rows] (27x64, rows padded to 32).
// Split Gram: Z ~ Th.Th^T + Th.Tl^T + Tl.Th^T via 3 MFMAs per k-slice.
// Output: Is[b][896] = [Ih(448) | Il(448)], I = [dx(64), triu(378), 0pad(6)]
__global__ __launch_bounds__(256)
void interact_k(const float* __restrict__ dxf, const int* __restrict__ sidx,
                const float* __restrict__ tables, u16* __restrict__ Is)
{
  const int lane = threadIdx.x & 63;
  const int b    = blockIdx.x * 4 + (threadIdx.x >> 6);
  const float* dxrow = dxf + (size_t)b * DIM;
  u16* irow = Is + (size_t)b * 896;

  // dense part, cols [0,64)
  {
    float v  = dxrow[lane];
    u16 hi = f2bf(v);
    u16 lo = f2bf(v - bf2f(hi));
    irow[lane] = hi; irow[448 + lane] = lo;
  }
  if (lane < 6) { irow[442 + lane] = 0; irow[448 + 442 + lane] = 0; }

  const int r    = lane & 31;
  const int half = lane >> 5;
  const float* src = nullptr;
  if (r == 0)       src = dxrow;
  else if (r <= 26) {
    int id = sidx[b * NTAB + (r - 1)];
    src = tables + ((size_t)(r - 1) * VOCAB + (size_t)id) * DIM;
  }

  short8 fh[4], fl[4];
  #pragma unroll
  for (int ks = 0; ks < 4; ++ks) {
    short8 h = {}, l = {};
    if (src) {
      const float* p = src + ks * 16 + half * 8;
      f32x4 a = *(const f32x4*)(p);
      f32x4 c = *(const f32x4*)(p + 4);
      #pragma unroll
      for (int j = 0; j < 4; ++j) {
        u16 ha = f2bf(a[j]); h[j]     = (short)ha; l[j]     = (short)f2bf(a[j] - bf2f(ha));
        u16 hc = f2bf(c[j]); h[j + 4] = (short)hc; l[j + 4] = (short)f2bf(c[j] - bf2f(hc));
      }
    }
    fh[ks] = h; fl[ks] = l;
  }

  f32x16 z = {};
  #pragma unroll
  for (int ks = 0; ks < 4; ++ks) {
    z = __builtin_amdgcn_mfma_f32_32x32x16_bf16(fh[ks], fh[ks], z, 0, 0, 0);
    z = __builtin_amdgcn_mfma_f32_32x32x16_bf16(fh[ks], fl[ks], z, 0, 0, 0);
    z = __builtin_amdgcn_mfma_f32_32x32x16_bf16(fl[ks], fh[ks], z, 0, 0, 0);
  }

  const int col = r;
  if (col < 27) {
    #pragma unroll
    for (int reg = 0; reg < 16; ++reg) {
      int rw = (reg & 3) + 8 * (reg >> 2) + 4 * half;
      if (rw <= col) {
        int flat = rw * 27 - rw * (rw - 1) / 2 + (col - rw);
        float v  = z[reg];
        u16 hi = f2bf(v);
        u16 lo = f2bf(v - bf2f(hi));
        irow[64 + flat] = hi; irow[448 + 64 + flat] = lo;
      }
    }
  }
}

// ---------------- finisher: out[b] = sigmoid(part0[b] + part1[b] + b3) ------------
__global__ __launch_bounds__(256)
void final2_k(const float* __restrict__ part, const float* __restrict__ b3,
              float* __restrict__ out)
{
  int i = blockIdx.x * 256 + threadIdx.x;
  float s = part[i] + part[BATCH + i] + b3[0];
  out[i] = 1.f / (1.f + expf(-s));
}

// ----------------------------------------------------------------------------------
extern "C" void kernel_launch(void* const* d_in, const int* in_sizes, int n_in,
                              void* d_out, int out_size, void* d_ws, size_t ws_size,
                              hipStream_t stream)
{
  const float* dense  = (const float*)d_in[0];
  const int*   sidx   = (const int*)d_in[1];
  const float* tables = (const float*)d_in[2];
  const float* bw1 = (const float*)d_in[3];  const float* bb1 = (const float*)d_in[4];
  const float* bw2 = (const float*)d_in[5];  const float* bb2 = (const float*)d_in[6];
  const float* bw3 = (const float*)d_in[7];  const float* bb3 = (const float*)d_in[8];
  const float* tw1 = (const float*)d_in[9];  const float* tb1 = (const float*)d_in[10];
  const float* tw2 = (const float*)d_in[11]; const float* tb2 = (const float*)d_in[12];
  const float* tw3 = (const float*)d_in[13]; const float* tb3 = (const float*)d_in[14];
  float* out = (float*)d_out;

  char* ws = (char*)d_ws;
  size_t off = 0;
  auto alloc = [&](size_t bytes) { size_t o = off; off += (bytes + 1023) & ~(size_t)1023; return o; };

  u16*  Xs   = (u16*)(ws + alloc((size_t)BATCH * 64 * 2));    // [B][2*32]
  u16*  W1s  = (u16*)(ws + alloc((size_t)512 * 64 * 2));      // [512][2*32]
  u16*  W2s  = (u16*)(ws + alloc((size_t)256 * 1024 * 2));    // [256][2*512]
  u16*  W3s  = (u16*)(ws + alloc((size_t)64 * 512 * 2));      // [64][2*256]
  u16*  WT1s = (u16*)(ws + alloc((size_t)512 * 896 * 2));     // [512][2*448]
  u16*  WT2s = (u16*)(ws + alloc((size_t)256 * 1024 * 2));    // [256][2*512]
  u16*  A1s  = (u16*)(ws + alloc((size_t)BATCH * 1024 * 2));  // [B][2*512] (reused as B1s)
  u16*  A2s  = (u16*)(ws + alloc((size_t)BATCH * 512 * 2));   // [B][2*256]
  float* dxf = (float*)(ws + alloc((size_t)BATCH * 64 * 4));  // [B][64] fp32
  u16*  Is   = (u16*)(ws + alloc((size_t)BATCH * 896 * 2));   // [B][2*448]
  float* part= (float*)(ws + alloc((size_t)2 * BATCH * 4));   // [2][B] fused-dot partials
  u16*  B1s  = A1s;  // A1s dead after bottom GEMM2; reuse for top-MLP hidden
  (void)ws_size; (void)n_in; (void)in_sizes; (void)out_size;

  // merged input conversion + tiled weight transpose/split (one launch)
  prep_k<<<2560, 256, 0, stream>>>(dense, Xs, bw1, W1s, bw2, W2s, bw3, W3s,
                                   tw1, WT1s, tw2, WT2s);

  // bottom MLP (dbuf-prefetched staging; B back in LDS)
  gemm_bt<128, 128, 32, 2, 2, 0><<<(BATCH / 128) * (512 / 128), 256, 0, stream>>>(
      Xs, W1s, bb1, A1s, 32, 512 / 128, 64, 64, 512, nullptr, nullptr);
  gemm_bt<128, 128, 64, 2, 2, 0><<<(BATCH / 128) * (256 / 128), 256, 0, stream>>>(
      A1s, W2s, bb2, A2s, 512, 256 / 128, 1024, 1024, 256, nullptr, nullptr);
  gemm_bt<128, 64, 64, 2, 1, 1><<<(BATCH / 128) * (64 / 64), 128, 0, stream>>>(
      A2s, W3s, bb3, dxf, 256, 64 / 64, 512, 512, 64, nullptr, nullptr);

  // gather + pairwise interaction (compact split output)
  interact_k<<<BATCH / 4, 256, 0, stream>>>(dxf, sidx, tables, Is);

  // top MLP (layer 3 fused into layer-2 epilogue as partial dots)
  gemm_bt<128, 128, 64, 2, 2, 0><<<(BATCH / 128) * (512 / 128), 256, 0, stream>>>(
      Is, WT1s, tb1, B1s, 448, 512 / 128, 896, 896, 512, nullptr, nullptr);
  gemm_bt<128, 128, 64, 2, 2, 2><<<(BATCH / 128) * (256 / 128), 256, 0, stream>>>(
      B1s, WT2s, tb2, nullptr, 512, 256 / 128, 1024, 1024, 256, tw3, part);
  final2_k<<<BATCH / 256, 256, 0, stream>>>(part, tb3, out);
}

// Round 8
// 131.494 us; speedup vs baseline: 1.2648x; 1.0673x over previous
//
#include <hip/hip_runtime.h>

typedef unsigned short u16;
typedef __attribute__((ext_vector_type(8))) short short8;
typedef __attribute__((ext_vector_type(4))) float f32x4;
typedef __attribute__((ext_vector_type(16))) float f32x16;

#define DEV __device__ __forceinline__

static constexpr int BATCH   = 16384;
static constexpr int NTAB    = 26;
static constexpr int VOCAB   = 100000;
static constexpr int DIM     = 64;

DEV u16 f2bf(float f){
  union { float f; unsigned u; } x; x.f = f;
  unsigned r = x.u + 0x7fffu + ((x.u >> 16) & 1u);
  return (u16)(r >> 16);
}
DEV float bf2f(u16 h){
  union { unsigned u; float f; } x; x.u = ((unsigned)h) << 16;
  return x.f;
}

// async global->LDS, 16B per lane. dst must be the wave-uniform base; HW adds lane*16.
DEV void llds16(u16* dst, const u16* src){
  __builtin_amdgcn_global_load_lds(
      (const __attribute__((address_space(1))) unsigned*)src,
      (__attribute__((address_space(3))) unsigned*)dst, 16, 0, 0);
}

// ---------------- prep: dense xsplit + tiled weight transpose/split ---------------
DEV void wtile(const float* __restrict__ src, u16* __restrict__ dst,
               int K, int N, int Kpad, int tile)
{
  __shared__ float ld[32][33];
  const int nt = N >> 5;
  const int k0 = (tile / nt) << 5;
  const int n0 = (tile % nt) << 5;
  const int tx = threadIdx.x & 31;   // fast dim
  const int ty = threadIdx.x >> 5;   // 8 rows per pass
  #pragma unroll
  for (int it = 0; it < 4; ++it) {
    int k = k0 + ty + 8 * it;
    ld[ty + 8 * it][tx] = (k < K) ? src[(size_t)k * N + n0 + tx] : 0.f;
  }
  __syncthreads();
  #pragma unroll
  for (int it = 0; it < 4; ++it) {
    int n  = n0 + ty + 8 * it;
    int kp = k0 + tx;
    float v = ld[tx][ty + 8 * it];
    u16 hi = f2bf(v);
    u16 lo = f2bf(v - bf2f(hi));
    u16* p = dst + (size_t)n * 2 * Kpad;
    p[kp] = hi; p[Kpad + kp] = lo;
  }
}

__global__ void prep_k(const float* __restrict__ dense, u16* __restrict__ Xs,
                       const float* __restrict__ bw1, u16* __restrict__ W1s,
                       const float* __restrict__ bw2, u16* __restrict__ W2s,
                       const float* __restrict__ bw3, u16* __restrict__ W3s,
                       const float* __restrict__ tw1, u16* __restrict__ WT1s,
                       const float* __restrict__ tw2, u16* __restrict__ WT2s)
{
  int blk = blockIdx.x;
  if (blk < 2048) {                       // dense: [B][13] -> [B][64] = [Ah(32)|Al(32)]
    int i = blk * 256 + threadIdx.x;      // B*32 items
    int b = i >> 5, k = i & 31;
    float v = (k < 13) ? dense[b * 13 + k] : 0.f;
    u16 hi = f2bf(v);
    u16 lo = f2bf(v - bf2f(hi));
    u16* p = Xs + (size_t)b * 64;
    p[k] = hi; p[32 + k] = lo;
  }
  else if (blk < 2064) wtile(bw1, W1s, 13, 512, 32,   blk - 2048);  // 1x16
  else if (blk < 2192) wtile(bw2, W2s, 512, 256, 512, blk - 2064);  // 16x8
  else if (blk < 2208) wtile(bw3, W3s, 256, 64, 256,  blk - 2192);  // 8x2
  else if (blk < 2432) wtile(tw1, WT1s, 442, 512, 448, blk - 2208); // 14x16
  else                 wtile(tw2, WT2s, 512, 256, 512, blk - 2432); // 16x8
}

// ---------------- GEMM: C[M][N] = relu(A * B^T + bias), split-fp32 emulation ------
// A stored [M][2*Khalf] = [Ah|Al]; Bt stored [N][2*Khalf] = [Bh|Bl].
// T3-min schedule (guide §5.5): per K-step ONE raw s_barrier + ONE vmcnt(0):
//   prologue stage(0); loop t: { vmcnt(0); s_barrier; stage(t+1,cur^1);
//   ds_read+MFMA from buf[cur]; }.
// stage(t+1) DMA flies under compute(t); head drain of t+1 is ~free. The head
// barrier also orders "reads of buf[cur^1] at t-1 done" before its re-stage.
// 32x32x16 bf16 MFMA; 3 combos (hi.hi + hi.lo + lo.hi); XOR-swizzled LDS.
// OUTMODE 0: compact split bf16 [M][2*ldc]=[Ch|Cl]. OUTMODE 1: fp32 [M][ldc].
// OUTMODE 2: fused last layer: part[(n0/BN)*BATCH + row] = sum_col relu(y)*w3[col].
template<int BM, int BN, int BK, int WM, int WN, int OUTMODE>
__global__ __launch_bounds__(WM * WN * 64)
void gemm_bt(const u16* __restrict__ A, const u16* __restrict__ Bt,
             const float* __restrict__ bias, void* __restrict__ Cout,
             int Khalf, int nbn, int lda, int ldb, int ldc,
             const float* __restrict__ w3, float* __restrict__ part)
{
  constexpr int THREADS = WM * WN * 64;
  constexpr int MI      = BM / (WM * 32);  // 32-row frags per wave (m)
  constexpr int NI      = BN / (WN * 32);  // 32-col frags per wave (n)
  constexpr int ROWB    = BK * 2;          // bytes per LDS row
  constexpr int SW      = ROWB / 16 - 1;   // swizzle mask over 16B slots
  constexpr int AIT     = (BM * ROWB) / (THREADS * 16);
  constexpr int BIT     = (BN * ROWB) / (THREADS * 16);

  __shared__ alignas(16) u16 Asm[2][2][BM * BK];  // [buf][hi|lo]
  __shared__ alignas(16) u16 Bsm[2][2][BN * BK];  // [buf][hi|lo]

  const int tid  = threadIdx.x;
  const int lane = tid & 63;
  const int wid  = tid >> 6;
  const int wm   = wid / WN;
  const int wn   = wid % WN;

  // T1: XCD-aware bijective chunk swizzle (all our grids are %8 == 0)
  int bid = blockIdx.x;
  {
    int nwg = gridDim.x;
    if ((nwg & 7) == 0) { int q = nwg >> 3; bid = (bid & 7) * q + (bid >> 3); }
  }
  const int m0   = (bid / nbn) * BM;
  const int n0   = (bid % nbn) * BN;
  const int l31  = lane & 31;
  const int half = lane >> 5;

  f32x16 acc[MI][NI] = {};

  auto stage = [&](int t, int buf) {
    const int k0s = t * BK;
    #pragma unroll
    for (int h = 0; h < 2; ++h) {
      const int koff = k0s + h * Khalf;   // hi section at k0, lo at Khalf+k0
      #pragma unroll
      for (int it = 0; it < AIT; ++it) {
        int loff = (it * THREADS + tid) * 16;
        int row  = loff / ROWB;
        int slot = (loff % ROWB) >> 4;
        int gs   = slot ^ (row & SW);
        llds16(&Asm[buf][h][(size_t)(it * THREADS + (wid << 6)) * 8],
               A + (size_t)(m0 + row) * lda + koff + gs * 8);
      }
      #pragma unroll
      for (int it = 0; it < BIT; ++it) {
        int loff = (it * THREADS + tid) * 16;
        int row  = loff / ROWB;
        int slot = (loff % ROWB) >> 4;
        int gs   = slot ^ (row & SW);
        llds16(&Bsm[buf][h][(size_t)(it * THREADS + (wid << 6)) * 8],
               Bt + (size_t)(n0 + row) * ldb + koff + gs * 8);
      }
    }
  };

  const int nsteps = Khalf / BK;
  stage(0, 0);                       // prologue
  int cur = 0;

  for (int t = 0; t < nsteps; ++t) {
    asm volatile("s_waitcnt vmcnt(0)" ::: "memory");  // own stage(t) loads landed
    __builtin_amdgcn_s_barrier();                     // all waves' loads landed;
                                                      // also: reads of buf[cur^1] done
    if (t + 1 < nsteps) stage(t + 1, cur ^ 1);        // DMA flies under compute

    #pragma unroll
    for (int ks = 0; ks < BK / 16; ++ks) {
      short8 ah[MI], al[MI], bh[NI], bl[NI];
      #pragma unroll
      for (int mi = 0; mi < MI; ++mi) {
        int row = wm * (MI * 32) + mi * 32 + l31;
        int sl  = (2 * ks + half) ^ (row & SW);
        ah[mi] = *(const short8*)(&Asm[cur][0][(size_t)row * BK + sl * 8]);
        al[mi] = *(const short8*)(&Asm[cur][1][(size_t)row * BK + sl * 8]);
      }
      #pragma unroll
      for (int ni = 0; ni < NI; ++ni) {
        int row = wn * (NI * 32) + ni * 32 + l31;
        int sl  = (2 * ks + half) ^ (row & SW);
        bh[ni] = *(const short8*)(&Bsm[cur][0][(size_t)row * BK + sl * 8]);
        bl[ni] = *(const short8*)(&Bsm[cur][1][(size_t)row * BK + sl * 8]);
      }
      #pragma unroll
      for (int mi = 0; mi < MI; ++mi)
        #pragma unroll
        for (int ni = 0; ni < NI; ++ni)
          acc[mi][ni] = __builtin_amdgcn_mfma_f32_32x32x16_bf16(
              ah[mi], bh[ni], acc[mi][ni], 0, 0, 0);
      #pragma unroll
      for (int mi = 0; mi < MI; ++mi)
        #pragma unroll
        for (int ni = 0; ni < NI; ++ni)
          acc[mi][ni] = __builtin_amdgcn_mfma_f32_32x32x16_bf16(
              ah[mi], bl[ni], acc[mi][ni], 0, 0, 0);
      #pragma unroll
      for (int mi = 0; mi < MI; ++mi)
        #pragma unroll
        for (int ni = 0; ni < NI; ++ni)
          acc[mi][ni] = __builtin_amdgcn_mfma_f32_32x32x16_bf16(
              al[mi], bh[ni], acc[mi][ni], 0, 0, 0);
    }
    cur ^= 1;
  }

  // epilogue. 32x32 C/D map: col = lane&31, row = (reg&3)+8*(reg>>2)+4*(lane>>5) [m74/m101]
  if constexpr (OUTMODE == 2) {
    // fused final layer: per-row partial dot of relu(y + bias) with w3
    __shared__ float redbuf[WN][BM];
    #pragma unroll
    for (int mi = 0; mi < MI; ++mi) {
      #pragma unroll
      for (int reg = 0; reg < 16; ++reg) {
        float s = 0.f;
        #pragma unroll
        for (int ni = 0; ni < NI; ++ni) {
          int col = n0 + wn * (NI * 32) + ni * 32 + l31;
          s += fmaxf(acc[mi][ni][reg] + bias[col], 0.f) * w3[col];
        }
        #pragma unroll
        for (int off = 16; off; off >>= 1) s += __shfl_xor(s, off);
        if (l31 == 0)
          redbuf[wn][wm * (MI * 32) + mi * 32 + (reg & 3) + 8 * (reg >> 2) + 4 * half] = s;
      }
    }
    __syncthreads();
    if (tid < BM) {
      float s = redbuf[0][tid];
      #pragma unroll
      for (int w = 1; w < WN; ++w) s += redbuf[w][tid];
      part[(size_t)(n0 / BN) * BATCH + m0 + tid] = s;
    }
  } else {
    #pragma unroll
    for (int ni = 0; ni < NI; ++ni) {
      int col  = n0 + wn * (NI * 32) + ni * 32 + l31;
      float bv = bias[col];
      #pragma unroll
      for (int mi = 0; mi < MI; ++mi) {
        #pragma unroll
        for (int reg = 0; reg < 16; ++reg) {
          int rowm = m0 + wm * (MI * 32) + mi * 32 + (reg & 3) + 8 * (reg >> 2) + 4 * half;
          float v  = fmaxf(acc[mi][ni][reg] + bv, 0.f);
          if (OUTMODE == 1) {
            ((float*)Cout)[(size_t)rowm * ldc + col] = v;
          } else {
            u16 hi = f2bf(v);
            u16 lo = f2bf(v - bf2f(hi));
            u16* p = (u16*)Cout + (size_t)rowm * 2 * ldc;
            p[col] = hi; p[ldc + col] = lo;
          }
        }
      }
    }
  }
}

// ---------------- interaction: gather + Z = T*T^T (triu), compact split out -------
__global__ __launch_bounds__(256)
void interact_k(const float* __restrict__ dxf, const int* __restrict__ sidx,
                const float* __restrict__ tables, u16* __restrict__ Is)
{
  const int lane = threadIdx.x & 63;
  const int b    = blockIdx.x * 4 + (threadIdx.x >> 6);
  const float* dxrow = dxf + (size_t)b * DIM;
  u16* irow = Is + (size_t)b * 896;

  // dense part, cols [0,64)
  {
    float v  = dxrow[lane];
    u16 hi = f2bf(v);
    u16 lo = f2bf(v - bf2f(hi));
    irow[lane] = hi; irow[448 + lane] = lo;
  }
  if (lane < 6) { irow[442 + lane] = 0; irow[448 + 442 + lane] = 0; }

  const int r    = lane & 31;
  const int half = lane >> 5;
  const float* src = nullptr;
  if (r == 0)       src = dxrow;
  else if (r <= 26) {
    int id = sidx[b * NTAB + (r - 1)];
    src = tables + ((size_t)(r - 1) * VOCAB + (size_t)id) * DIM;
  }

  short8 fh[4], fl[4];
  #pragma unroll
  for (int ks = 0; ks < 4; ++ks) {
    short8 h = {}, l = {};
    if (src) {
      const float* p = src + ks * 16 + half * 8;
      f32x4 a = *(const f32x4*)(p);
      f32x4 c = *(const f32x4*)(p + 4);
      #pragma unroll
      for (int j = 0; j < 4; ++j) {
        u16 ha = f2bf(a[j]); h[j]     = (short)ha; l[j]     = (short)f2bf(a[j] - bf2f(ha));
        u16 hc = f2bf(c[j]); h[j + 4] = (short)hc; l[j + 4] = (short)f2bf(c[j] - bf2f(hc));
      }
    }
    fh[ks] = h; fl[ks] = l;
  }

  f32x16 z = {};
  #pragma unroll
  for (int ks = 0; ks < 4; ++ks) {
    z = __builtin_amdgcn_mfma_f32_32x32x16_bf16(fh[ks], fh[ks], z, 0, 0, 0);
    z = __builtin_amdgcn_mfma_f32_32x32x16_bf16(fh[ks], fl[ks], z, 0, 0, 0);
    z = __builtin_amdgcn_mfma_f32_32x32x16_bf16(fl[ks], fh[ks], z, 0, 0, 0);
  }

  const int col = r;
  if (col < 27) {
    #pragma unroll
    for (int reg = 0; reg < 16; ++reg) {
      int rw = (reg & 3) + 8 * (reg >> 2) + 4 * half;
      if (rw <= col) {
        int flat = rw * 27 - rw * (rw - 1) / 2 + (col - rw);
        float v  = z[reg];
        u16 hi = f2bf(v);
        u16 lo = f2bf(v - bf2f(hi));
        irow[64 + flat] = hi; irow[448 + 64 + flat] = lo;
      }
    }
  }
}

// ---------------- finisher: out[b] = sigmoid(part0[b] + part1[b] + b3) ------------
__global__ __launch_bounds__(256)
void final2_k(const float* __restrict__ part, const float* __restrict__ b3,
              float* __restrict__ out)
{
  int i = blockIdx.x * 256 + threadIdx.x;
  float s = part[i] + part[BATCH + i] + b3[0];
  out[i] = 1.f / (1.f + expf(-s));
}

// ----------------------------------------------------------------------------------
extern "C" void kernel_launch(void* const* d_in, const int* in_sizes, int n_in,
                              void* d_out, int out_size, void* d_ws, size_t ws_size,
                              hipStream_t stream)
{
  const float* dense  = (const float*)d_in[0];
  const int*   sidx   = (const int*)d_in[1];
  const float* tables = (const float*)d_in[2];
  const float* bw1 = (const float*)d_in[3];  const float* bb1 = (const float*)d_in[4];
  const float* bw2 = (const float*)d_in[5];  const float* bb2 = (const float*)d_in[6];
  const float* bw3 = (const float*)d_in[7];  const float* bb3 = (const float*)d_in[8];
  const float* tw1 = (const float*)d_in[9];  const float* tb1 = (const float*)d_in[10];
  const float* tw2 = (const float*)d_in[11]; const float* tb2 = (const float*)d_in[12];
  const float* tw3 = (const float*)d_in[13]; const float* tb3 = (const float*)d_in[14];
  float* out = (float*)d_out;

  char* ws = (char*)d_ws;
  size_t off = 0;
  auto alloc = [&](size_t bytes) { size_t o = off; off += (bytes + 1023) & ~(size_t)1023; return o; };

  u16*  Xs   = (u16*)(ws + alloc((size_t)BATCH * 64 * 2));    // [B][2*32]
  u16*  W1s  = (u16*)(ws + alloc((size_t)512 * 64 * 2));      // [512][2*32]
  u16*  W2s  = (u16*)(ws + alloc((size_t)256 * 1024 * 2));    // [256][2*512]
  u16*  W3s  = (u16*)(ws + alloc((size_t)64 * 512 * 2));      // [64][2*256]
  u16*  WT1s = (u16*)(ws + alloc((size_t)512 * 896 * 2));     // [512][2*448]
  u16*  WT2s = (u16*)(ws + alloc((size_t)256 * 1024 * 2));    // [256][2*512]
  u16*  A1s  = (u16*)(ws + alloc((size_t)BATCH * 1024 * 2));  // [B][2*512] (reused as B1s)
  u16*  A2s  = (u16*)(ws + alloc((size_t)BATCH * 512 * 2));   // [B][2*256]
  float* dxf = (float*)(ws + alloc((size_t)BATCH * 64 * 4));  // [B][64] fp32
  u16*  Is   = (u16*)(ws + alloc((size_t)BATCH * 896 * 2));   // [B][2*448]
  float* part= (float*)(ws + alloc((size_t)2 * BATCH * 4));   // [2][B] fused-dot partials
  u16*  B1s  = A1s;  // A1s dead after bottom GEMM2; reuse for top-MLP hidden
  (void)ws_size; (void)n_in; (void)in_sizes; (void)out_size;

  // merged input conversion + tiled weight transpose/split (one launch)
  prep_k<<<2560, 256, 0, stream>>>(dense, Xs, bw1, W1s, bw2, W2s, bw3, W3s,
                                   tw1, WT1s, tw2, WT2s);

  // bottom MLP (T3-min schedule; 8 waves on the big GEMMs)
  gemm_bt<128, 128, 32, 2, 4, 0><<<(BATCH / 128) * (512 / 128), 512, 0, stream>>>(
      Xs, W1s, bb1, A1s, 32, 512 / 128, 64, 64, 512, nullptr, nullptr);
  gemm_bt<128, 128, 64, 2, 4, 0><<<(BATCH / 128) * (256 / 128), 512, 0, stream>>>(
      A1s, W2s, bb2, A2s, 512, 256 / 128, 1024, 1024, 256, nullptr, nullptr);
  gemm_bt<64, 64, 64, 1, 2, 1><<<(BATCH / 64) * (64 / 64), 128, 0, stream>>>(
      A2s, W3s, bb3, dxf, 256, 64 / 64, 512, 512, 64, nullptr, nullptr);

  // gather + pairwise interaction (compact split output)
  interact_k<<<BATCH / 4, 256, 0, stream>>>(dxf, sidx, tables, Is);

  // top MLP (layer 3 fused into layer-2 epilogue as partial dots)
  gemm_bt<128, 128, 64, 2, 4, 0><<<(BATCH / 128) * (512 / 128), 512, 0, stream>>>(
      Is, WT1s, tb1, B1s, 448, 512 / 128, 896, 896, 512, nullptr, nullptr);
  gemm_bt<128, 128, 64, 2, 4, 2><<<(BATCH / 128) * (256 / 128), 512, 0, stream>>>(
      B1s, WT2s, tb2, nullptr, 512, 256 / 128, 1024, 1024, 256, tw3, part);
  final2_k<<<BATCH / 256, 256, 0, stream>>>(part, tb3, out);
}

// Round 9
// 119.293 us; speedup vs baseline: 1.3942x; 1.1023x over previous
//
#include <hip/hip_runtime.h>

typedef unsigned short u16;
typedef _Float16 f16;
typedef __attribute__((ext_vector_type(8))) _Float16 half8;
typedef __attribute__((ext_vector_type(4))) float f32x4;
typedef __attribute__((ext_vector_type(16))) float f32x16;

#define DEV __device__ __forceinline__

static constexpr int BATCH   = 16384;
static constexpr int NTAB    = 26;
static constexpr int VOCAB   = 100000;
static constexpr int DIM     = 64;

DEV u16 f2h(float f){ union { f16 h; u16 u; } x; x.h = (f16)f; return x.u; }
DEV float h2f(u16 b){ union { u16 u; f16 h; } x; x.u = b; return (float)x.h; }

// async global->LDS, 16B per lane. dst must be the wave-uniform base; HW adds lane*16.
DEV void llds16(u16* dst, const u16* src){
  __builtin_amdgcn_global_load_lds(
      (const __attribute__((address_space(1))) unsigned*)src,
      (__attribute__((address_space(3))) unsigned*)dst, 16, 0, 0);
}

// ---------------- prep: dense xsplit + tiled weight transpose (single fp16) -------
// Weights (B-side) are SINGLE fp16 [N][Kpad]; activations (A-side) are split fp16.
DEV void wtile(const float* __restrict__ src, u16* __restrict__ dst,
               int K, int N, int Kpad, int tile)
{
  __shared__ float ld[32][33];
  const int nt = N >> 5;
  const int k0 = (tile / nt) << 5;
  const int n0 = (tile % nt) << 5;
  const int tx = threadIdx.x & 31;   // fast dim
  const int ty = threadIdx.x >> 5;   // 8 rows per pass
  #pragma unroll
  for (int it = 0; it < 4; ++it) {
    int k = k0 + ty + 8 * it;
    ld[ty + 8 * it][tx] = (k < K) ? src[(size_t)k * N + n0 + tx] : 0.f;
  }
  __syncthreads();
  #pragma unroll
  for (int it = 0; it < 4; ++it) {
    int n  = n0 + ty + 8 * it;
    int kp = k0 + tx;
    dst[(size_t)n * Kpad + kp] = f2h(ld[tx][ty + 8 * it]);
  }
}

__global__ void prep_k(const float* __restrict__ dense, u16* __restrict__ Xs,
                       const float* __restrict__ bw1, u16* __restrict__ W1s,
                       const float* __restrict__ bw2, u16* __restrict__ W2s,
                       const float* __restrict__ bw3, u16* __restrict__ W3s,
                       const float* __restrict__ tw1, u16* __restrict__ WT1s,
                       const float* __restrict__ tw2, u16* __restrict__ WT2s)
{
  int blk = blockIdx.x;
  if (blk < 2048) {                       // dense: [B][13] -> [B][64] = [Ah(32)|Al(32)]
    int i = blk * 256 + threadIdx.x;      // B*32 items
    int b = i >> 5, k = i & 31;
    float v = (k < 13) ? dense[b * 13 + k] : 0.f;
    u16 hi = f2h(v);
    u16 lo = f2h(v - h2f(hi));
    u16* p = Xs + (size_t)b * 64;
    p[k] = hi; p[32 + k] = lo;
  }
  else if (blk < 2064) wtile(bw1, W1s, 13, 512, 32,   blk - 2048);  // 1x16
  else if (blk < 2192) wtile(bw2, W2s, 512, 256, 512, blk - 2064);  // 16x8
  else if (blk < 2208) wtile(bw3, W3s, 256, 64, 256,  blk - 2192);  // 8x2
  else if (blk < 2432) wtile(tw1, WT1s, 442, 512, 448, blk - 2208); // 14x16
  else                 wtile(tw2, WT2s, 512, 256, 512, blk - 2432); // 16x8
}

// ---------------- GEMM: C[M][N] = relu(A * B^T + bias), fp16 asymmetric split -----
// A stored split fp16 [M][2*Khalf] = [Ah|Al] (22-bit); Bt single fp16 [N][Khalf].
// C = Ah.B + Al.B (2 combos; B-side error 2^-11 only). T3-min schedule: per K-step
// one raw s_barrier + one vmcnt(0); stage(t+1) issued right after the barrier so
// DMA flies under compute. 32x32x16 f16 MFMA, XOR-swizzled LDS.
// OUTMODE 0: compact split fp16 [M][2*ldc]=[Ch|Cl]. OUTMODE 1: fp32 [M][ldc].
// OUTMODE 2: fused last layer: part[(n0/BN)*BATCH + row] = sum_col relu(y)*w3[col].
template<int BM, int BN, int BK, int WM, int WN, int OUTMODE>
__global__ __launch_bounds__(WM * WN * 64)
void gemm_bt(const u16* __restrict__ A, const u16* __restrict__ Bt,
             const float* __restrict__ bias, void* __restrict__ Cout,
             int Khalf, int nbn, int lda, int ldb, int ldc,
             const float* __restrict__ w3, float* __restrict__ part)
{
  constexpr int THREADS = WM * WN * 64;
  constexpr int MI      = BM / (WM * 32);  // 32-row frags per wave (m)
  constexpr int NI      = BN / (WN * 32);  // 32-col frags per wave (n)
  constexpr int ROWB    = BK * 2;          // bytes per LDS row
  constexpr int SW      = ROWB / 16 - 1;   // swizzle mask over 16B slots
  constexpr int AIT     = (BM * ROWB) / (THREADS * 16);
  constexpr int BIT     = (BN * ROWB) / (THREADS * 16);

  __shared__ alignas(16) u16 Asm[2][2][BM * BK];  // [buf][hi|lo]
  __shared__ alignas(16) u16 Bsm[2][BN * BK];     // [buf] single

  const int tid  = threadIdx.x;
  const int lane = tid & 63;
  const int wid  = tid >> 6;
  const int wm   = wid / WN;
  const int wn   = wid % WN;

  // T1: XCD-aware bijective chunk swizzle (all our grids are %8 == 0)
  int bid = blockIdx.x;
  {
    int nwg = gridDim.x;
    if ((nwg & 7) == 0) { int q = nwg >> 3; bid = (bid & 7) * q + (bid >> 3); }
  }
  const int m0   = (bid / nbn) * BM;
  const int n0   = (bid % nbn) * BN;
  const int l31  = lane & 31;
  const int half = lane >> 5;

  f32x16 acc[MI][NI] = {};

  auto stage = [&](int t, int buf) {
    const int k0s = t * BK;
    #pragma unroll
    for (int h = 0; h < 2; ++h) {
      const int koff = k0s + h * Khalf;   // A: hi section at k0, lo at Khalf+k0
      #pragma unroll
      for (int it = 0; it < AIT; ++it) {
        int loff = (it * THREADS + tid) * 16;
        int row  = loff / ROWB;
        int slot = (loff % ROWB) >> 4;
        int gs   = slot ^ (row & SW);
        llds16(&Asm[buf][h][(size_t)(it * THREADS + (wid << 6)) * 8],
               A + (size_t)(m0 + row) * lda + koff + gs * 8);
      }
    }
    #pragma unroll
    for (int it = 0; it < BIT; ++it) {
      int loff = (it * THREADS + tid) * 16;
      int row  = loff / ROWB;
      int slot = (loff % ROWB) >> 4;
      int gs   = slot ^ (row & SW);
      llds16(&Bsm[buf][(size_t)(it * THREADS + (wid << 6)) * 8],
             Bt + (size_t)(n0 + row) * ldb + k0s + gs * 8);
    }
  };

  const int nsteps = Khalf / BK;
  stage(0, 0);                       // prologue
  int cur = 0;

  for (int t = 0; t < nsteps; ++t) {
    asm volatile("s_waitcnt vmcnt(0)" ::: "memory");  // own stage(t) loads landed
    __builtin_amdgcn_s_barrier();                     // all waves' loads landed;
                                                      // also: reads of buf[cur^1] done
    if (t + 1 < nsteps) stage(t + 1, cur ^ 1);        // DMA flies under compute

    #pragma unroll
    for (int ks = 0; ks < BK / 16; ++ks) {
      half8 ah[MI], al[MI], bf[NI];
      #pragma unroll
      for (int mi = 0; mi < MI; ++mi) {
        int row = wm * (MI * 32) + mi * 32 + l31;
        int sl  = (2 * ks + half) ^ (row & SW);
        ah[mi] = *(const half8*)(&Asm[cur][0][(size_t)row * BK + sl * 8]);
        al[mi] = *(const half8*)(&Asm[cur][1][(size_t)row * BK + sl * 8]);
      }
      #pragma unroll
      for (int ni = 0; ni < NI; ++ni) {
        int row = wn * (NI * 32) + ni * 32 + l31;
        int sl  = (2 * ks + half) ^ (row & SW);
        bf[ni] = *(const half8*)(&Bsm[cur][(size_t)row * BK + sl * 8]);
      }
      #pragma unroll
      for (int mi = 0; mi < MI; ++mi)
        #pragma unroll
        for (int ni = 0; ni < NI; ++ni)
          acc[mi][ni] = __builtin_amdgcn_mfma_f32_32x32x16_f16(
              ah[mi], bf[ni], acc[mi][ni], 0, 0, 0);
      #pragma unroll
      for (int mi = 0; mi < MI; ++mi)
        #pragma unroll
        for (int ni = 0; ni < NI; ++ni)
          acc[mi][ni] = __builtin_amdgcn_mfma_f32_32x32x16_f16(
              al[mi], bf[ni], acc[mi][ni], 0, 0, 0);
    }
    cur ^= 1;
  }

  // epilogue. 32x32 C/D map: col = lane&31, row = (reg&3)+8*(reg>>2)+4*(lane>>5) [m74/m101]
  if constexpr (OUTMODE == 2) {
    // fused final layer: per-row partial dot of relu(y + bias) with w3
    __shared__ float redbuf[WN][BM];
    #pragma unroll
    for (int mi = 0; mi < MI; ++mi) {
      #pragma unroll
      for (int reg = 0; reg < 16; ++reg) {
        float s = 0.f;
        #pragma unroll
        for (int ni = 0; ni < NI; ++ni) {
          int col = n0 + wn * (NI * 32) + ni * 32 + l31;
          s += fmaxf(acc[mi][ni][reg] + bias[col], 0.f) * w3[col];
        }
        #pragma unroll
        for (int off = 16; off; off >>= 1) s += __shfl_xor(s, off);
        if (l31 == 0)
          redbuf[wn][wm * (MI * 32) + mi * 32 + (reg & 3) + 8 * (reg >> 2) + 4 * half] = s;
      }
    }
    __syncthreads();
    if (tid < BM) {
      float s = redbuf[0][tid];
      #pragma unroll
      for (int w = 1; w < WN; ++w) s += redbuf[w][tid];
      part[(size_t)(n0 / BN) * BATCH + m0 + tid] = s;
    }
  } else {
    #pragma unroll
    for (int ni = 0; ni < NI; ++ni) {
      int col  = n0 + wn * (NI * 32) + ni * 32 + l31;
      float bv = bias[col];
      #pragma unroll
      for (int mi = 0; mi < MI; ++mi) {
        #pragma unroll
        for (int reg = 0; reg < 16; ++reg) {
          int rowm = m0 + wm * (MI * 32) + mi * 32 + (reg & 3) + 8 * (reg >> 2) + 4 * half;
          float v  = fmaxf(acc[mi][ni][reg] + bv, 0.f);
          if (OUTMODE == 1) {
            ((float*)Cout)[(size_t)rowm * ldc + col] = v;
          } else {
            u16 hi = f2h(v);
            u16 lo = f2h(v - h2f(hi));
            u16* p = (u16*)Cout + (size_t)rowm * 2 * ldc;
            p[col] = hi; p[ldc + col] = lo;
          }
        }
      }
    }
  }
}

// ---------------- interaction: gather + Z = T*T^T (triu), split fp16 out ----------
// One wave per batch row. T = [dx; 26 embedding rows] (27x64, rows padded to 32).
// fp16 asymmetric Gram: Z ~ Th.Th^T + Tl.Th^T (B-side error 2^-11).
// Output: Is[b][896] = [Ih(448) | Il(448)], I = [dx(64), triu(378), 0pad(6)]
__global__ __launch_bounds__(256)
void interact_k(const float* __restrict__ dxf, const int* __restrict__ sidx,
                const float* __restrict__ tables, u16* __restrict__ Is)
{
  const int lane = threadIdx.x & 63;
  const int b    = blockIdx.x * 4 + (threadIdx.x >> 6);
  const float* dxrow = dxf + (size_t)b * DIM;
  u16* irow = Is + (size_t)b * 896;

  // dense part, cols [0,64)
  {
    float v  = dxrow[lane];
    u16 hi = f2h(v);
    u16 lo = f2h(v - h2f(hi));
    irow[lane] = hi; irow[448 + lane] = lo;
  }
  if (lane < 6) { irow[442 + lane] = 0; irow[448 + 442 + lane] = 0; }

  const int r    = lane & 31;
  const int half = lane >> 5;
  const float* src = nullptr;
  if (r == 0)       src = dxrow;
  else if (r <= 26) {
    int id = sidx[b * NTAB + (r - 1)];
    src = tables + ((size_t)(r - 1) * VOCAB + (size_t)id) * DIM;
  }

  half8 fh[4], fl[4];
  #pragma unroll
  for (int ks = 0; ks < 4; ++ks) {
    half8 h = {}, l = {};
    if (src) {
      const float* p = src + ks * 16 + half * 8;
      f32x4 a = *(const f32x4*)(p);
      f32x4 c = *(const f32x4*)(p + 4);
      #pragma unroll
      for (int j = 0; j < 4; ++j) {
        h[j]     = (f16)a[j]; l[j]     = (f16)(a[j] - (float)h[j]);
        h[j + 4] = (f16)c[j]; l[j + 4] = (f16)(c[j] - (float)h[j + 4]);
      }
    }
    fh[ks] = h; fl[ks] = l;
  }

  f32x16 z = {};
  #pragma unroll
  for (int ks = 0; ks < 4; ++ks) {
    z = __builtin_amdgcn_mfma_f32_32x32x16_f16(fh[ks], fh[ks], z, 0, 0, 0);
    z = __builtin_amdgcn_mfma_f32_32x32x16_f16(fl[ks], fh[ks], z, 0, 0, 0);
  }

  const int col = r;
  if (col < 27) {
    #pragma unroll
    for (int reg = 0; reg < 16; ++reg) {
      int rw = (reg & 3) + 8 * (reg >> 2) + 4 * half;
      if (rw <= col) {
        int flat = rw * 27 - rw * (rw - 1) / 2 + (col - rw);
        float v  = z[reg];
        u16 hi = f2h(v);
        u16 lo = f2h(v - h2f(hi));
        irow[64 + flat] = hi; irow[448 + 64 + flat] = lo;
      }
    }
  }
}

// ---------------- finisher: out[b] = sigmoid(part0[b] + part1[b] + b3) ------------
__global__ __launch_bounds__(256)
void final2_k(const float* __restrict__ part, const float* __restrict__ b3,
              float* __restrict__ out)
{
  int i = blockIdx.x * 256 + threadIdx.x;
  float s = part[i] + part[BATCH + i] + b3[0];
  out[i] = 1.f / (1.f + expf(-s));
}

// ----------------------------------------------------------------------------------
extern "C" void kernel_launch(void* const* d_in, const int* in_sizes, int n_in,
                              void* d_out, int out_size, void* d_ws, size_t ws_size,
                              hipStream_t stream)
{
  const float* dense  = (const float*)d_in[0];
  const int*   sidx   = (const int*)d_in[1];
  const float* tables = (const float*)d_in[2];
  const float* bw1 = (const float*)d_in[3];  const float* bb1 = (const float*)d_in[4];
  const float* bw2 = (const float*)d_in[5];  const float* bb2 = (const float*)d_in[6];
  const float* bw3 = (const float*)d_in[7];  const float* bb3 = (const float*)d_in[8];
  const float* tw1 = (const float*)d_in[9];  const float* tb1 = (const float*)d_in[10];
  const float* tw2 = (const float*)d_in[11]; const float* tb2 = (const float*)d_in[12];
  const float* tw3 = (const float*)d_in[13]; const float* tb3 = (const float*)d_in[14];
  float* out = (float*)d_out;

  char* ws = (char*)d_ws;
  size_t off = 0;
  auto alloc = [&](size_t bytes) { size_t o = off; off += (bytes + 1023) & ~(size_t)1023; return o; };

  u16*  Xs   = (u16*)(ws + alloc((size_t)BATCH * 64 * 2));    // [B][2*32] split
  u16*  W1s  = (u16*)(ws + alloc((size_t)512 * 32 * 2));      // [512][32] single
  u16*  W2s  = (u16*)(ws + alloc((size_t)256 * 512 * 2));     // [256][512]
  u16*  W3s  = (u16*)(ws + alloc((size_t)64 * 256 * 2));      // [64][256]
  u16*  WT1s = (u16*)(ws + alloc((size_t)512 * 448 * 2));     // [512][448]
  u16*  WT2s = (u16*)(ws + alloc((size_t)256 * 512 * 2));     // [256][512]
  u16*  A1s  = (u16*)(ws + alloc((size_t)BATCH * 1024 * 2));  // [B][2*512] (reused as B1s)
  u16*  A2s  = (u16*)(ws + alloc((size_t)BATCH * 512 * 2));   // [B][2*256]
  float* dxf = (float*)(ws + alloc((size_t)BATCH * 64 * 4));  // [B][64] fp32
  u16*  Is   = (u16*)(ws + alloc((size_t)BATCH * 896 * 2));   // [B][2*448]
  float* part= (float*)(ws + alloc((size_t)2 * BATCH * 4));   // [2][B] fused-dot partials
  u16*  B1s  = A1s;  // A1s dead after bottom GEMM2; reuse for top-MLP hidden
  (void)ws_size; (void)n_in; (void)in_sizes; (void)out_size;

  // merged input conversion + tiled weight transpose (one launch)
  prep_k<<<2560, 256, 0, stream>>>(dense, Xs, bw1, W1s, bw2, W2s, bw3, W3s,
                                   tw1, WT1s, tw2, WT2s);

  // bottom MLP (T3-min schedule; fp16 2-combo)
  gemm_bt<128, 128, 32, 2, 4, 0><<<(BATCH / 128) * (512 / 128), 512, 0, stream>>>(
      Xs, W1s, bb1, A1s, 32, 512 / 128, 64, 32, 512, nullptr, nullptr);
  gemm_bt<128, 128, 64, 2, 4, 0><<<(BATCH / 128) * (256 / 128), 512, 0, stream>>>(
      A1s, W2s, bb2, A2s, 512, 256 / 128, 1024, 512, 256, nullptr, nullptr);
  gemm_bt<64, 64, 64, 1, 2, 1><<<(BATCH / 64) * (64 / 64), 128, 0, stream>>>(
      A2s, W3s, bb3, dxf, 256, 64 / 64, 512, 256, 64, nullptr, nullptr);

  // gather + pairwise interaction (split fp16 output)
  interact_k<<<BATCH / 4, 256, 0, stream>>>(dxf, sidx, tables, Is);

  // top MLP (layer 3 fused into layer-2 epilogue as partial dots)
  gemm_bt<128, 128, 64, 2, 4, 0><<<(BATCH / 128) * (512 / 128), 512, 0, stream>>>(
      Is, WT1s, tb1, B1s, 448, 512 / 128, 896, 448, 512, nullptr, nullptr);
  gemm_bt<128, 128, 64, 2, 4, 2><<<(BATCH / 128) * (256 / 128), 512, 0, stream>>>(
      B1s, WT2s, tb2, nullptr, 512, 256 / 128, 1024, 512, 256, tw3, part);
  final2_k<<<BATCH / 256, 256, 0, stream>>>(part, tb3, out);
}

// Round 10
// 89.353 us; speedup vs baseline: 1.8614x; 1.3351x over previous
//
#include <hip/hip_runtime.h>

typedef unsigned short u16;
typedef _Float16 f16;
typedef __attribute__((ext_vector_type(8))) _Float16 half8;
typedef __attribute__((ext_vector_type(4))) float f32x4;
typedef __attribute__((ext_vector_type(16))) float f32x16;

#define DEV __device__ __forceinline__

static constexpr int BATCH   = 16384;
static constexpr int NTAB    = 26;
static constexpr int VOCAB   = 100000;
static constexpr int DIM     = 64;

DEV u16 f2h(float f){ union { f16 h; u16 u; } x; x.h = (f16)f; return x.u; }
DEV float h2f(u16 b){ union { u16 u; f16 h; } x; x.u = b; return (float)x.h; }

// async global->LDS, 16B per lane. dst must be the wave-uniform base; HW adds lane*16.
DEV void llds16(u16* dst, const u16* src){
  __builtin_amdgcn_global_load_lds(
      (const __attribute__((address_space(1))) unsigned*)src,
      (__attribute__((address_space(3))) unsigned*)dst, 16, 0, 0);
}

// ---------------- prep: dense conv + tiled weight transpose (single fp16) ---------
DEV void wtile(const float* __restrict__ src, u16* __restrict__ dst,
               int K, int N, int Kpad, int tile)
{
  __shared__ float ld[32][33];
  const int nt = N >> 5;
  const int k0 = (tile / nt) << 5;
  const int n0 = (tile % nt) << 5;
  const int tx = threadIdx.x & 31;   // fast dim
  const int ty = threadIdx.x >> 5;   // 8 rows per pass
  #pragma unroll
  for (int it = 0; it < 4; ++it) {
    int k = k0 + ty + 8 * it;
    ld[ty + 8 * it][tx] = (k < K) ? src[(size_t)k * N + n0 + tx] : 0.f;
  }
  __syncthreads();
  #pragma unroll
  for (int it = 0; it < 4; ++it) {
    int n  = n0 + ty + 8 * it;
    int kp = k0 + tx;
    dst[(size_t)n * Kpad + kp] = f2h(ld[tx][ty + 8 * it]);
  }
}

__global__ void prep_k(const float* __restrict__ dense, u16* __restrict__ Xs,
                       const float* __restrict__ bw1, u16* __restrict__ W1s,
                       const float* __restrict__ bw2, u16* __restrict__ W2s,
                       const float* __restrict__ bw3, u16* __restrict__ W3s,
                       const float* __restrict__ tw1, u16* __restrict__ WT1s,
                       const float* __restrict__ tw2, u16* __restrict__ WT2s)
{
  int blk = blockIdx.x;
  if (blk < 2048) {                       // dense: [B][13] -> [B][32] fp16 (0-pad)
    int i = blk * 256 + threadIdx.x;      // B*32 items
    int b = i >> 5, k = i & 31;
    float v = (k < 13) ? dense[b * 13 + k] : 0.f;
    Xs[(size_t)b * 32 + k] = f2h(v);
  }
  else if (blk < 2064) wtile(bw1, W1s, 13, 512, 32,   blk - 2048);  // 1x16
  else if (blk < 2192) wtile(bw2, W2s, 512, 256, 512, blk - 2064);  // 16x8
  else if (blk < 2208) wtile(bw3, W3s, 256, 64, 256,  blk - 2192);  // 8x2
  else if (blk < 2432) wtile(tw1, WT1s, 442, 512, 448, blk - 2208); // 14x16
  else                 wtile(tw2, WT2s, 512, 256, 512, blk - 2432); // 16x8
}

// ---------------- GEMM: C[M][N] = relu(A * B^T + bias), single fp16 ---------------
// A fp16 [M][K]; Bt fp16 [N][K]. T3-min schedule: per K-step one raw s_barrier +
// one vmcnt(0); stage(t+1) issued right after the barrier so DMA flies under
// compute. 32x32x16 f16 MFMA, XOR-swizzled LDS, XCD-swizzled blockIdx.
// OUTMODE 0: fp16 [M][ldc]. OUTMODE 1: fp32 [M][ldc].
// OUTMODE 2: fused last layer: part[(n0/BN)*BATCH + row] = sum_col relu(y)*w3[col].
template<int BM, int BN, int BK, int WM, int WN, int OUTMODE>
__global__ __launch_bounds__(WM * WN * 64)
void gemm_bt(const u16* __restrict__ A, const u16* __restrict__ Bt,
             const float* __restrict__ bias, void* __restrict__ Cout,
             int K, int nbn, int lda, int ldb, int ldc,
             const float* __restrict__ w3, float* __restrict__ part)
{
  constexpr int THREADS = WM * WN * 64;
  constexpr int MI      = BM / (WM * 32);  // 32-row frags per wave (m)
  constexpr int NI      = BN / (WN * 32);  // 32-col frags per wave (n)
  constexpr int ROWB    = BK * 2;          // bytes per LDS row
  constexpr int SW      = ROWB / 16 - 1;   // swizzle mask over 16B slots
  constexpr int AIT     = (BM * ROWB) / (THREADS * 16);
  constexpr int BIT     = (BN * ROWB) / (THREADS * 16);

  __shared__ alignas(16) u16 Asm[2][BM * BK];  // [buf]
  __shared__ alignas(16) u16 Bsm[2][BN * BK];  // [buf]

  const int tid  = threadIdx.x;
  const int lane = tid & 63;
  const int wid  = tid >> 6;
  const int wm   = wid / WN;
  const int wn   = wid % WN;

  // T1: XCD-aware bijective chunk swizzle (all our grids are %8 == 0)
  int bid = blockIdx.x;
  {
    int nwg = gridDim.x;
    if ((nwg & 7) == 0) { int q = nwg >> 3; bid = (bid & 7) * q + (bid >> 3); }
  }
  const int m0   = (bid / nbn) * BM;
  const int n0   = (bid % nbn) * BN;
  const int l31  = lane & 31;
  const int half = lane >> 5;

  f32x16 acc[MI][NI] = {};

  auto stage = [&](int t, int buf) {
    const int k0s = t * BK;
    #pragma unroll
    for (int it = 0; it < AIT; ++it) {
      int loff = (it * THREADS + tid) * 16;
      int row  = loff / ROWB;
      int slot = (loff % ROWB) >> 4;
      int gs   = slot ^ (row & SW);
      llds16(&Asm[buf][(size_t)(it * THREADS + (wid << 6)) * 8],
             A + (size_t)(m0 + row) * lda + k0s + gs * 8);
    }
    #pragma unroll
    for (int it = 0; it < BIT; ++it) {
      int loff = (it * THREADS + tid) * 16;
      int row  = loff / ROWB;
      int slot = (loff % ROWB) >> 4;
      int gs   = slot ^ (row & SW);
      llds16(&Bsm[buf][(size_t)(it * THREADS + (wid << 6)) * 8],
             Bt + (size_t)(n0 + row) * ldb + k0s + gs * 8);
    }
  };

  const int nsteps = K / BK;
  stage(0, 0);                       // prologue
  int cur = 0;

  for (int t = 0; t < nsteps; ++t) {
    asm volatile("s_waitcnt vmcnt(0)" ::: "memory");  // own stage(t) loads landed
    __builtin_amdgcn_s_barrier();                     // all waves' loads landed;
                                                      // also: reads of buf[cur^1] done
    if (t + 1 < nsteps) stage(t + 1, cur ^ 1);        // DMA flies under compute

    #pragma unroll
    for (int ks = 0; ks < BK / 16; ++ks) {
      half8 af[MI], bf[NI];
      #pragma unroll
      for (int mi = 0; mi < MI; ++mi) {
        int row = wm * (MI * 32) + mi * 32 + l31;
        int sl  = (2 * ks + half) ^ (row & SW);
        af[mi] = *(const half8*)(&Asm[cur][(size_t)row * BK + sl * 8]);
      }
      #pragma unroll
      for (int ni = 0; ni < NI; ++ni) {
        int row = wn * (NI * 32) + ni * 32 + l31;
        int sl  = (2 * ks + half) ^ (row & SW);
        bf[ni] = *(const half8*)(&Bsm[cur][(size_t)row * BK + sl * 8]);
      }
      #pragma unroll
      for (int mi = 0; mi < MI; ++mi)
        #pragma unroll
        for (int ni = 0; ni < NI; ++ni)
          acc[mi][ni] = __builtin_amdgcn_mfma_f32_32x32x16_f16(
              af[mi], bf[ni], acc[mi][ni], 0, 0, 0);
    }
    cur ^= 1;
  }

  // epilogue. 32x32 C/D map: col = lane&31, row = (reg&3)+8*(reg>>2)+4*(lane>>5) [m74/m101]
  if constexpr (OUTMODE == 2) {
    // fused final layer: per-row partial dot of relu(y + bias) with w3
    __shared__ float redbuf[WN][BM];
    #pragma unroll
    for (int mi = 0; mi < MI; ++mi) {
      #pragma unroll
      for (int reg = 0; reg < 16; ++reg) {
        float s = 0.f;
        #pragma unroll
        for (int ni = 0; ni < NI; ++ni) {
          int col = n0 + wn * (NI * 32) + ni * 32 + l31;
          s += fmaxf(acc[mi][ni][reg] + bias[col], 0.f) * w3[col];
        }
        #pragma unroll
        for (int off = 16; off; off >>= 1) s += __shfl_xor(s, off);
        if (l31 == 0)
          redbuf[wn][wm * (MI * 32) + mi * 32 + (reg & 3) + 8 * (reg >> 2) + 4 * half] = s;
      }
    }
    __syncthreads();
    if (tid < BM) {
      float s = redbuf[0][tid];
      #pragma unroll
      for (int w = 1; w < WN; ++w) s += redbuf[w][tid];
      part[(size_t)(n0 / BN) * BATCH + m0 + tid] = s;
    }
  } else {
    #pragma unroll
    for (int ni = 0; ni < NI; ++ni) {
      int col  = n0 + wn * (NI * 32) + ni * 32 + l31;
      float bv = bias[col];
      #pragma unroll
      for (int mi = 0; mi < MI; ++mi) {
        #pragma unroll
        for (int reg = 0; reg < 16; ++reg) {
          int rowm = m0 + wm * (MI * 32) + mi * 32 + (reg & 3) + 8 * (reg >> 2) + 4 * half;
          float v  = fmaxf(acc[mi][ni][reg] + bv, 0.f);
          if (OUTMODE == 1) ((float*)Cout)[(size_t)rowm * ldc + col] = v;
          else              ((u16*)Cout)[(size_t)rowm * ldc + col] = f2h(v);
        }
      }
    }
  }
}

// ---------------- interaction: gather + Z = T*T^T (triu), single fp16 out ---------
// One wave per batch row. T = [dx; 26 embedding rows] (27x64, rows padded to 32).
// Output: Is[b][448] = [dx(64), triu(378), 0pad(6)] fp16.
__global__ __launch_bounds__(256)
void interact_k(const float* __restrict__ dxf, const int* __restrict__ sidx,
                const float* __restrict__ tables, u16* __restrict__ Is)
{
  const int lane = threadIdx.x & 63;
  const int b    = blockIdx.x * 4 + (threadIdx.x >> 6);
  const float* dxrow = dxf + (size_t)b * DIM;
  u16* irow = Is + (size_t)b * 448;

  // dense part, cols [0,64)
  irow[lane] = f2h(dxrow[lane]);
  if (lane < 6) irow[442 + lane] = 0;

  const int r    = lane & 31;
  const int half = lane >> 5;
  const float* src = nullptr;
  if (r == 0)       src = dxrow;
  else if (r <= 26) {
    int id = sidx[b * NTAB + (r - 1)];
    src = tables + ((size_t)(r - 1) * VOCAB + (size_t)id) * DIM;
  }

  half8 fh[4];
  #pragma unroll
  for (int ks = 0; ks < 4; ++ks) {
    half8 h = {};
    if (src) {
      const float* p = src + ks * 16 + half * 8;
      f32x4 a = *(const f32x4*)(p);
      f32x4 c = *(const f32x4*)(p + 4);
      #pragma unroll
      for (int j = 0; j < 4; ++j) { h[j] = (f16)a[j]; h[j + 4] = (f16)c[j]; }
    }
    fh[ks] = h;
  }

  f32x16 z = {};
  #pragma unroll
  for (int ks = 0; ks < 4; ++ks)
    z = __builtin_amdgcn_mfma_f32_32x32x16_f16(fh[ks], fh[ks], z, 0, 0, 0);

  const int col = r;
  if (col < 27) {
    #pragma unroll
    for (int reg = 0; reg < 16; ++reg) {
      int rw = (reg & 3) + 8 * (reg >> 2) + 4 * half;
      if (rw <= col) {
        int flat = rw * 27 - rw * (rw - 1) / 2 + (col - rw);
        irow[64 + flat] = f2h(z[reg]);
      }
    }
  }
}

// ---------------- finisher: out[b] = sigmoid(part0[b] + part1[b] + b3) ------------
__global__ __launch_bounds__(256)
void final2_k(const float* __restrict__ part, const float* __restrict__ b3,
              float* __restrict__ out)
{
  int i = blockIdx.x * 256 + threadIdx.x;
  float s = part[i] + part[BATCH + i] + b3[0];
  out[i] = 1.f / (1.f + expf(-s));
}

// ----------------------------------------------------------------------------------
extern "C" void kernel_launch(void* const* d_in, const int* in_sizes, int n_in,
                              void* d_out, int out_size, void* d_ws, size_t ws_size,
                              hipStream_t stream)
{
  const float* dense  = (const float*)d_in[0];
  const int*   sidx   = (const int*)d_in[1];
  const float* tables = (const float*)d_in[2];
  const float* bw1 = (const float*)d_in[3];  const float* bb1 = (const float*)d_in[4];
  const float* bw2 = (const float*)d_in[5];  const float* bb2 = (const float*)d_in[6];
  const float* bw3 = (const float*)d_in[7];  const float* bb3 = (const float*)d_in[8];
  const float* tw1 = (const float*)d_in[9];  const float* tb1 = (const float*)d_in[10];
  const float* tw2 = (const float*)d_in[11]; const float* tb2 = (const float*)d_in[12];
  const float* tw3 = (const float*)d_in[13]; const float* tb3 = (const float*)d_in[14];
  float* out = (float*)d_out;

  char* ws = (char*)d_ws;
  size_t off = 0;
  auto alloc = [&](size_t bytes) { size_t o = off; off += (bytes + 1023) & ~(size_t)1023; return o; };

  u16*  Xs   = (u16*)(ws + alloc((size_t)BATCH * 32 * 2));    // [B][32]
  u16*  W1s  = (u16*)(ws + alloc((size_t)512 * 32 * 2));      // [512][32]
  u16*  W2s  = (u16*)(ws + alloc((size_t)256 * 512 * 2));     // [256][512]
  u16*  W3s  = (u16*)(ws + alloc((size_t)64 * 256 * 2));      // [64][256]
  u16*  WT1s = (u16*)(ws + alloc((size_t)512 * 448 * 2));     // [512][448]
  u16*  WT2s = (u16*)(ws + alloc((size_t)256 * 512 * 2));     // [256][512]
  u16*  A1s  = (u16*)(ws + alloc((size_t)BATCH * 512 * 2));   // [B][512] (reused as B1s)
  u16*  A2s  = (u16*)(ws + alloc((size_t)BATCH * 256 * 2));   // [B][256]
  float* dxf = (float*)(ws + alloc((size_t)BATCH * 64 * 4));  // [B][64] fp32
  u16*  Is   = (u16*)(ws + alloc((size_t)BATCH * 448 * 2));   // [B][448]
  float* part= (float*)(ws + alloc((size_t)2 * BATCH * 4));   // [2][B] fused-dot partials
  u16*  B1s  = A1s;  // A1s dead after bottom GEMM2; reuse for top-MLP hidden
  (void)ws_size; (void)n_in; (void)in_sizes; (void)out_size;

  // merged input conversion + tiled weight transpose (one launch)
  prep_k<<<2560, 256, 0, stream>>>(dense, Xs, bw1, W1s, bw2, W2s, bw3, W3s,
                                   tw1, WT1s, tw2, WT2s);

  // bottom MLP (T3-min schedule; single fp16)
  gemm_bt<128, 128, 32, 2, 4, 0><<<(BATCH / 128) * (512 / 128), 512, 0, stream>>>(
      Xs, W1s, bb1, A1s, 32, 512 / 128, 32, 32, 512, nullptr, nullptr);
  gemm_bt<128, 128, 64, 2, 4, 0><<<(BATCH / 128) * (256 / 128), 512, 0, stream>>>(
      A1s, W2s, bb2, A2s, 512, 256 / 128, 512, 512, 256, nullptr, nullptr);
  gemm_bt<64, 64, 64, 1, 2, 1><<<(BATCH / 64) * (64 / 64), 128, 0, stream>>>(
      A2s, W3s, bb3, dxf, 256, 64 / 64, 256, 256, 64, nullptr, nullptr);

  // gather + pairwise interaction (single fp16 output)
  interact_k<<<BATCH / 4, 256, 0, stream>>>(dxf, sidx, tables, Is);

  // top MLP (layer 3 fused into layer-2 epilogue as partial dots)
  gemm_bt<128, 128, 64, 2, 4, 0><<<(BATCH / 128) * (512 / 128), 512, 0, stream>>>(
      Is, WT1s, tb1, B1s, 448, 512 / 128, 448, 448, 512, nullptr, nullptr);
  gemm_bt<128, 128, 64, 2, 4, 2><<<(BATCH / 128) * (256 / 128), 512, 0, stream>>>(
      B1s, WT2s, tb2, nullptr, 512, 256 / 128, 512, 512, 256, tw3, part);
  final2_k<<<BATCH / 256, 256, 0, stream>>>(part, tb3, out);
}

// Round 11
// 82.481 us; speedup vs baseline: 2.0165x; 1.0833x over previous
//
#include <hip/hip_runtime.h>

typedef unsigned short u16;
typedef _Float16 f16;
typedef __attribute__((ext_vector_type(8))) _Float16 half8;
typedef __attribute__((ext_vector_type(4))) float f32x4;
typedef __attribute__((ext_vector_type(16))) float f32x16;

#define DEV __device__ __forceinline__

static constexpr int BATCH   = 16384;
static constexpr int NTAB    = 26;
static constexpr int VOCAB   = 100000;
static constexpr int DIM     = 64;

DEV u16 f2h(float f){ union { f16 h; u16 u; } x; x.h = (f16)f; return x.u; }

// async global->LDS, 16B per lane. dst must be the wave-uniform base; HW adds lane*16.
DEV void llds16(u16* dst, const u16* src){
  __builtin_amdgcn_global_load_lds(
      (const __attribute__((address_space(1))) unsigned*)src,
      (__attribute__((address_space(3))) unsigned*)dst, 16, 0, 0);
}

DEV int crow(int reg, int half){ return (reg & 3) + 8 * (reg >> 2) + 4 * half; }

// ---------------- prep: dense conv + tiled weight transpose (single fp16) ---------
DEV void wtile(const float* __restrict__ src, u16* __restrict__ dst,
               int K, int N, int Kpad, int tile)
{
  __shared__ float ld[32][33];
  const int nt = N >> 5;
  const int k0 = (tile / nt) << 5;
  const int n0 = (tile % nt) << 5;
  const int tx = threadIdx.x & 31;
  const int ty = threadIdx.x >> 5;
  #pragma unroll
  for (int it = 0; it < 4; ++it) {
    int k = k0 + ty + 8 * it;
    ld[ty + 8 * it][tx] = (k < K) ? src[(size_t)k * N + n0 + tx] : 0.f;
  }
  __syncthreads();
  #pragma unroll
  for (int it = 0; it < 4; ++it) {
    int n  = n0 + ty + 8 * it;
    int kp = k0 + tx;
    dst[(size_t)n * Kpad + kp] = f2h(ld[tx][ty + 8 * it]);
  }
}

__global__ void prep_k(const float* __restrict__ dense, u16* __restrict__ Xs,
                       const float* __restrict__ bw1, u16* __restrict__ W1s,
                       const float* __restrict__ bw2, u16* __restrict__ W2s,
                       const float* __restrict__ bw3, u16* __restrict__ W3s,
                       const float* __restrict__ tw1, u16* __restrict__ WT1s,
                       const float* __restrict__ tw2, u16* __restrict__ WT2s)
{
  int blk = blockIdx.x;
  if (blk < 2048) {                       // dense: [B][13] -> [B][32] fp16 (0-pad)
    int i = blk * 256 + threadIdx.x;
    int b = i >> 5, k = i & 31;
    float v = (k < 13) ? dense[b * 13 + k] : 0.f;
    Xs[(size_t)b * 32 + k] = f2h(v);
  }
  else if (blk < 2064) wtile(bw1, W1s, 13, 512, 32,    blk - 2048);  // 16
  else if (blk < 2192) wtile(bw2, W2s, 512, 256, 512,  blk - 2064);  // 128
  else if (blk < 2208) wtile(bw3, W3s, 256, 64, 256,   blk - 2192);  // 16
  else if (blk < 2464) wtile(tw1, WT1s, 442, 512, 512, blk - 2208);  // 256 (K padded)
  else                 wtile(tw2, WT2s, 512, 256, 512, blk - 2464);  // 128
}

// ---------------- fused bottom MLP: X -> A1 -> A2 -> dx, one block per 64 rows ----
// LDS: A1 [64][512] SW=63 | S(68KB): {X[64][32],W1[512][32]} / W2 tiles / A2,W3.
// All GEMM fragments use the verified XOR-swizzle patterns; weight tiles staged
// from L2 with T3-min prefetch (stage(t+1) after head barrier, one vmcnt per step).
__global__ __launch_bounds__(256)
void bottom_mlp_k(const u16* __restrict__ Xs, const u16* __restrict__ W1s,
                  const u16* __restrict__ W2s, const u16* __restrict__ W3s,
                  const float* __restrict__ bb1, const float* __restrict__ bb2,
                  const float* __restrict__ bb3, float* __restrict__ dxf)
{
  __shared__ alignas(16) u16 lds[67584];           // 132 KB
  u16* A1  = lds;                                  // [64][512] SW=63
  u16* S   = lds + 32768;
  u16* Xl  = S;                                    // [64][32]  SW=3
  u16* W1l = S + 2048;                             // [512][32] SW=3
  u16* W2b0 = S + 18432;                           // [256][64] SW=7
  u16* W2b1 = S;
  u16* A2  = S + 18432;                            // [64][256] SW=31
  u16* W3l = S;                                    // [64][256] SW=31

  const int tid = threadIdx.x, lane = tid & 63, wid = tid >> 6;
  int bid = blockIdx.x;
  bid = (bid & 7) * 32 + (bid >> 3);               // XCD swizzle (256 blocks)
  const int m0  = bid * 64;
  const int l31 = lane & 31, half = lane >> 5;

  auto stageW2 = [&](int t, u16* buf) {
    #pragma unroll
    for (int it = 0; it < 8; ++it) {
      int loff = (it * 256 + tid) * 16;
      int row  = loff >> 7, slot = (loff & 127) >> 4, gs = slot ^ (row & 7);
      llds16(buf + (size_t)(it * 256 + (wid << 6)) * 8,
             W2s + (size_t)row * 512 + t * 64 + gs * 8);
    }
  };

  // stage X + W1; prefetch W2(0) under G1
  {
    int loff = tid * 16, row = loff >> 6, slot = (loff & 63) >> 4, gs = slot ^ (row & 3);
    llds16(Xl + (size_t)(wid << 6) * 8, Xs + (size_t)(m0 + row) * 32 + gs * 8);
  }
  #pragma unroll
  for (int it = 0; it < 8; ++it) {
    int loff = (it * 256 + tid) * 16, row = loff >> 6, slot = (loff & 63) >> 4,
        gs = slot ^ (row & 3);
    llds16(W1l + (size_t)(it * 256 + (wid << 6)) * 8, W1s + (size_t)row * 32 + gs * 8);
  }
  stageW2(0, W2b0);
  asm volatile("s_waitcnt vmcnt(8)" ::: "memory");  // X+W1 landed; W2(0) in flight
  __builtin_amdgcn_s_barrier();

  // G1: A1 = relu(X * W1^T + bb1), K=32
  f32x16 acc1[2][4] = {};
  #pragma unroll
  for (int ks = 0; ks < 2; ++ks) {
    half8 af[2], bf[4];
    #pragma unroll
    for (int mi = 0; mi < 2; ++mi) {
      int row = mi * 32 + l31, sl = (2 * ks + half) ^ (row & 3);
      af[mi] = *(const half8*)(Xl + (size_t)row * 32 + sl * 8);
    }
    #pragma unroll
    for (int ni = 0; ni < 4; ++ni) {
      int row = wid * 128 + ni * 32 + l31, sl = (2 * ks + half) ^ (row & 3);
      bf[ni] = *(const half8*)(W1l + (size_t)row * 32 + sl * 8);
    }
    #pragma unroll
    for (int mi = 0; mi < 2; ++mi)
      #pragma unroll
      for (int ni = 0; ni < 4; ++ni)
        acc1[mi][ni] = __builtin_amdgcn_mfma_f32_32x32x16_f16(af[mi], bf[ni], acc1[mi][ni], 0, 0, 0);
  }
  #pragma unroll
  for (int ni = 0; ni < 4; ++ni) {
    int col = wid * 128 + ni * 32 + l31;
    float bv = bb1[col];
    #pragma unroll
    for (int mi = 0; mi < 2; ++mi)
      #pragma unroll
      for (int reg = 0; reg < 16; ++reg) {
        int row = mi * 32 + crow(reg, half);
        float v = fmaxf(acc1[mi][ni][reg] + bv, 0.f);
        A1[(size_t)row * 512 + (((col >> 3) ^ (row & 63)) * 8) + (col & 7)] = f2h(v);
      }
  }
  __syncthreads();

  // G2: A2 = relu(A1 * W2^T + bb2), K=512, 8 steps BK=64
  f32x16 acc2[2][2] = {};
  for (int t = 0; t < 8; ++t) {
    asm volatile("s_waitcnt vmcnt(0)" ::: "memory");
    __builtin_amdgcn_s_barrier();
    if (t < 7) stageW2(t + 1, ((t + 1) & 1) ? W2b1 : W2b0);
    const u16* buf = (t & 1) ? W2b1 : W2b0;
    #pragma unroll
    for (int ks = 0; ks < 4; ++ks) {
      int s = t * 4 + ks;
      half8 af[2], bf[2];
      #pragma unroll
      for (int mi = 0; mi < 2; ++mi) {
        int row = mi * 32 + l31, sl = (2 * s + half) ^ (row & 63);
        af[mi] = *(const half8*)(A1 + (size_t)row * 512 + sl * 8);
      }
      #pragma unroll
      for (int ni = 0; ni < 2; ++ni) {
        int row = wid * 64 + ni * 32 + l31, sl = (2 * ks + half) ^ (row & 7);
        bf[ni] = *(const half8*)(buf + (size_t)row * 64 + sl * 8);
      }
      #pragma unroll
      for (int mi = 0; mi < 2; ++mi)
        #pragma unroll
        for (int ni = 0; ni < 2; ++ni)
          acc2[mi][ni] = __builtin_amdgcn_mfma_f32_32x32x16_f16(af[mi], bf[ni], acc2[mi][ni], 0, 0, 0);
    }
  }
  // epilogue -> A2 (overlays W2b0; all waves past step-7 head barrier => buf0 reads done)
  #pragma unroll
  for (int ni = 0; ni < 2; ++ni) {
    int col = wid * 64 + ni * 32 + l31;
    float bv = bb2[col];
    #pragma unroll
    for (int mi = 0; mi < 2; ++mi)
      #pragma unroll
      for (int reg = 0; reg < 16; ++reg) {
        int row = mi * 32 + crow(reg, half);
        float v = fmaxf(acc2[mi][ni][reg] + bv, 0.f);
        A2[(size_t)row * 256 + (((col >> 3) ^ (row & 31)) * 8) + (col & 7)] = f2h(v);
      }
  }
  __syncthreads();

  // stage full W3 [64][256] (32 KB, overlays W2b1)
  #pragma unroll
  for (int it = 0; it < 8; ++it) {
    int loff = (it * 256 + tid) * 16;
    int row = loff >> 9, slot = (loff & 511) >> 4, gs = slot ^ (row & 31);
    llds16(W3l + (size_t)(it * 256 + (wid << 6)) * 8, W3s + (size_t)row * 256 + gs * 8);
  }
  asm volatile("s_waitcnt vmcnt(0)" ::: "memory");
  __builtin_amdgcn_s_barrier();

  // G3: dx[64][64] = relu(A2 * W3^T + bb3), K=256
  f32x16 acc3 = {};
  const int gm = (wid >> 1) * 32, gn = (wid & 1) * 32;
  #pragma unroll
  for (int s = 0; s < 16; ++s) {
    int rowa = gm + l31, sa = (2 * s + half) ^ (rowa & 31);
    half8 a = *(const half8*)(A2 + (size_t)rowa * 256 + sa * 8);
    int rowb = gn + l31, sb = (2 * s + half) ^ (rowb & 31);
    half8 b = *(const half8*)(W3l + (size_t)rowb * 256 + sb * 8);
    acc3 = __builtin_amdgcn_mfma_f32_32x32x16_f16(a, b, acc3, 0, 0, 0);
  }
  #pragma unroll
  for (int reg = 0; reg < 16; ++reg) {
    int col = gn + l31, row = gm + crow(reg, half);
    dxf[(size_t)(m0 + row) * 64 + col] = fmaxf(acc3[reg] + bb3[col], 0.f);
  }
}

// ---------------- interaction: gather + Z = T*T^T (triu), fp16 out [B][512] -------
__global__ __launch_bounds__(256)
void interact_k(const float* __restrict__ dxf, const int* __restrict__ sidx,
                const float* __restrict__ tables, u16* __restrict__ Is)
{
  const int lane = threadIdx.x & 63;
  const int b    = blockIdx.x * 4 + (threadIdx.x >> 6);
  const float* dxrow = dxf + (size_t)b * DIM;
  u16* irow = Is + (size_t)b * 512;

  irow[lane] = f2h(dxrow[lane]);
  irow[442 + lane] = 0;                 // zero-pad 442..505
  if (lane < 6) irow[506 + lane] = 0;   // zero-pad 506..511

  const int r    = lane & 31;
  const int half = lane >> 5;
  const float* src = nullptr;
  if (r == 0)       src = dxrow;
  else if (r <= 26) {
    int id = sidx[b * NTAB + (r - 1)];
    src = tables + ((size_t)(r - 1) * VOCAB + (size_t)id) * DIM;
  }

  half8 fh[4];
  #pragma unroll
  for (int ks = 0; ks < 4; ++ks) {
    half8 h = {};
    if (src) {
      const float* p = src + ks * 16 + half * 8;
      f32x4 a = *(const f32x4*)(p);
      f32x4 c = *(const f32x4*)(p + 4);
      #pragma unroll
      for (int j = 0; j < 4; ++j) { h[j] = (f16)a[j]; h[j + 4] = (f16)c[j]; }
    }
    fh[ks] = h;
  }

  f32x16 z = {};
  #pragma unroll
  for (int ks = 0; ks < 4; ++ks)
    z = __builtin_amdgcn_mfma_f32_32x32x16_f16(fh[ks], fh[ks], z, 0, 0, 0);

  const int col = r;
  if (col < 27) {
    #pragma unroll
    for (int reg = 0; reg < 16; ++reg) {
      int rw = crow(reg, half);
      if (rw <= col) {
        int flat = rw * 27 - rw * (rw - 1) / 2 + (col - rw);
        irow[64 + flat] = f2h(z[reg]);
      }
    }
  }
}

// ---------------- fused top MLP: Is -> B1 -> y -> dot(w3) -> sigmoid -> out -------
// LDS: AB [64][512] (Is, then B1 in-place) SW=63 | W tiles 2x32KB.
// G4 K padded to 512; W4 tile row-pair-packed (128B phys rows, XOR over 8 slots).
__global__ __launch_bounds__(256)
void top_mlp_k(const u16* __restrict__ Is, const u16* __restrict__ WT1s,
               const u16* __restrict__ WT2s, const float* __restrict__ tb1,
               const float* __restrict__ tb2, const float* __restrict__ tw3,
               const float* __restrict__ tb3, float* __restrict__ out)
{
  __shared__ alignas(16) u16 lds[65536];           // 128 KB
  __shared__ float redbuf[4][64];
  u16* AB  = lds;                                  // [64][512] SW=63
  u16* Wb0 = lds + 32768;
  u16* Wb1 = lds + 49152;

  const int tid = threadIdx.x, lane = tid & 63, wid = tid >> 6;
  int bid = blockIdx.x;
  bid = (bid & 7) * 32 + (bid >> 3);               // XCD swizzle (256 blocks)
  const int m0  = bid * 64;
  const int l31 = lane & 31, half = lane >> 5;

  // W4 tile: logical [512][32] stored row-pair-packed: phys row pr=n>>1 (128 B),
  // phys slot = (4*(n&1) + logslot) ^ (pr&7). Inverse applied on global source.
  auto stageW4 = [&](int t, u16* buf) {
    #pragma unroll
    for (int it = 0; it < 8; ++it) {
      int p  = (it * 256 + tid) * 16;
      int pr = p >> 7, ps = (p & 127) >> 4;
      int un = ps ^ (pr & 7);
      int row = 2 * pr + (un >> 2), ls = un & 3;
      llds16(buf + (size_t)(it * 256 + (wid << 6)) * 8,
             WT1s + (size_t)row * 512 + t * 32 + ls * 8);
    }
  };
  auto stageW5 = [&](int t, u16* buf) {
    #pragma unroll
    for (int it = 0; it < 8; ++it) {
      int loff = (it * 256 + tid) * 16;
      int row = loff >> 7, slot = (loff & 127) >> 4, gs = slot ^ (row & 7);
      llds16(buf + (size_t)(it * 256 + (wid << 6)) * 8,
             WT2s + (size_t)row * 512 + t * 64 + gs * 8);
    }
  };

  // stage Is strip [64][512]; prefetch W4(0)
  #pragma unroll
  for (int it = 0; it < 16; ++it) {
    int loff = (it * 256 + tid) * 16;
    int row = loff >> 10, slot = (loff & 1023) >> 4, gs = slot ^ (row & 63);
    llds16(AB + (size_t)(it * 256 + (wid << 6)) * 8,
           Is + (size_t)(m0 + row) * 512 + gs * 8);
  }
  stageW4(0, Wb0);

  // G4: B1 = relu(Is * WT1^T + tb1), K=512, 16 steps BK=32
  f32x16 acc4[2][4] = {};
  for (int t = 0; t < 16; ++t) {
    asm volatile("s_waitcnt vmcnt(0)" ::: "memory");
    __builtin_amdgcn_s_barrier();
    if (t < 15) stageW4(t + 1, ((t + 1) & 1) ? Wb1 : Wb0);
    const u16* buf = (t & 1) ? Wb1 : Wb0;
    #pragma unroll
    for (int ks = 0; ks < 2; ++ks) {
      int s = t * 2 + ks;
      half8 af[2], bf[4];
      #pragma unroll
      for (int mi = 0; mi < 2; ++mi) {
        int row = mi * 32 + l31, sl = (2 * s + half) ^ (row & 63);
        af[mi] = *(const half8*)(AB + (size_t)row * 512 + sl * 8);
      }
      #pragma unroll
      for (int ni = 0; ni < 4; ++ni) {
        int n = wid * 128 + ni * 32 + l31;
        int pr = n >> 1;
        int ps = (4 * (n & 1) + 2 * ks + half) ^ (pr & 7);
        bf[ni] = *(const half8*)(buf + (size_t)pr * 64 + ps * 8);
      }
      #pragma unroll
      for (int mi = 0; mi < 2; ++mi)
        #pragma unroll
        for (int ni = 0; ni < 4; ++ni)
          acc4[mi][ni] = __builtin_amdgcn_mfma_f32_32x32x16_f16(af[mi], bf[ni], acc4[mi][ni], 0, 0, 0);
    }
  }
  __syncthreads();                                  // all Is reads done
  #pragma unroll
  for (int ni = 0; ni < 4; ++ni) {
    int col = wid * 128 + ni * 32 + l31;
    float bv = tb1[col];
    #pragma unroll
    for (int mi = 0; mi < 2; ++mi)
      #pragma unroll
      for (int reg = 0; reg < 16; ++reg) {
        int row = mi * 32 + crow(reg, half);
        float v = fmaxf(acc4[mi][ni][reg] + bv, 0.f);
        AB[(size_t)row * 512 + (((col >> 3) ^ (row & 63)) * 8) + (col & 7)] = f2h(v);
      }
  }
  __syncthreads();

  // G5: y = relu(B1 * WT2^T + tb2), K=512, 8 steps BK=64; fused final dot
  stageW5(0, Wb0);
  f32x16 acc5[2][2] = {};
  for (int t = 0; t < 8; ++t) {
    asm volatile("s_waitcnt vmcnt(0)" ::: "memory");
    __builtin_amdgcn_s_barrier();
    if (t < 7) stageW5(t + 1, ((t + 1) & 1) ? Wb1 : Wb0);
    const u16* buf = (t & 1) ? Wb1 : Wb0;
    #pragma unroll
    for (int ks = 0; ks < 4; ++ks) {
      int s = t * 4 + ks;
      half8 af[2], bf[2];
      #pragma unroll
      for (int mi = 0; mi < 2; ++mi) {
        int row = mi * 32 + l31, sl = (2 * s + half) ^ (row & 63);
        af[mi] = *(const half8*)(AB + (size_t)row * 512 + sl * 8);
      }
      #pragma unroll
      for (int ni = 0; ni < 2; ++ni) {
        int row = wid * 64 + ni * 32 + l31, sl = (2 * ks + half) ^ (row & 7);
        bf[ni] = *(const half8*)(buf + (size_t)row * 64 + sl * 8);
      }
      #pragma unroll
      for (int mi = 0; mi < 2; ++mi)
        #pragma unroll
        for (int ni = 0; ni < 2; ++ni)
          acc5[mi][ni] = __builtin_amdgcn_mfma_f32_32x32x16_f16(af[mi], bf[ni], acc5[mi][ni], 0, 0, 0);
    }
  }
  // fused final layer: per-row dot of relu(y) with tw3, then sigmoid
  float bv[2], wv[2];
  #pragma unroll
  for (int ni = 0; ni < 2; ++ni) {
    int col = wid * 64 + ni * 32 + l31;
    bv[ni] = tb2[col]; wv[ni] = tw3[col];
  }
  #pragma unroll
  for (int mi = 0; mi < 2; ++mi)
    #pragma unroll
    for (int reg = 0; reg < 16; ++reg) {
      float s = 0.f;
      #pragma unroll
      for (int ni = 0; ni < 2; ++ni)
        s += fmaxf(acc5[mi][ni][reg] + bv[ni], 0.f) * wv[ni];
      #pragma unroll
      for (int off = 16; off; off >>= 1) s += __shfl_xor(s, off);
      if (l31 == 0) redbuf[wid][mi * 32 + crow(reg, half)] = s;
    }
  __syncthreads();
  if (tid < 64) {
    float s = redbuf[0][tid] + redbuf[1][tid] + redbuf[2][tid] + redbuf[3][tid] + tb3[0];
    out[m0 + tid] = 1.f / (1.f + expf(-s));
  }
}

// ----------------------------------------------------------------------------------
extern "C" void kernel_launch(void* const* d_in, const int* in_sizes, int n_in,
                              void* d_out, int out_size, void* d_ws, size_t ws_size,
                              hipStream_t stream)
{
  const float* dense  = (const float*)d_in[0];
  const int*   sidx   = (const int*)d_in[1];
  const float* tables = (const float*)d_in[2];
  const float* bw1 = (const float*)d_in[3];  const float* bb1 = (const float*)d_in[4];
  const float* bw2 = (const float*)d_in[5];  const float* bb2 = (const float*)d_in[6];
  const float* bw3 = (const float*)d_in[7];  const float* bb3 = (const float*)d_in[8];
  const float* tw1 = (const float*)d_in[9];  const float* tb1 = (const float*)d_in[10];
  const float* tw2 = (const float*)d_in[11]; const float* tb2 = (const float*)d_in[12];
  const float* tw3 = (const float*)d_in[13]; const float* tb3 = (const float*)d_in[14];
  float* out = (float*)d_out;

  char* ws = (char*)d_ws;
  size_t off = 0;
  auto alloc = [&](size_t bytes) { size_t o = off; off += (bytes + 1023) & ~(size_t)1023; return o; };

  u16*  Xs   = (u16*)(ws + alloc((size_t)BATCH * 32 * 2));    // [B][32]
  u16*  W1s  = (u16*)(ws + alloc((size_t)512 * 32 * 2));      // [512][32]
  u16*  W2s  = (u16*)(ws + alloc((size_t)256 * 512 * 2));     // [256][512]
  u16*  W3s  = (u16*)(ws + alloc((size_t)64 * 256 * 2));      // [64][256]
  u16*  WT1s = (u16*)(ws + alloc((size_t)512 * 512 * 2));     // [512][512] (K padded)
  u16*  WT2s = (u16*)(ws + alloc((size_t)256 * 512 * 2));     // [256][512]
  float* dxf = (float*)(ws + alloc((size_t)BATCH * 64 * 4));  // [B][64] fp32
  u16*  Is   = (u16*)(ws + alloc((size_t)BATCH * 512 * 2));   // [B][512]
  (void)ws_size; (void)n_in; (void)in_sizes; (void)out_size;

  prep_k<<<2592, 256, 0, stream>>>(dense, Xs, bw1, W1s, bw2, W2s, bw3, W3s,
                                   tw1, WT1s, tw2, WT2s);
  bottom_mlp_k<<<256, 256, 0, stream>>>(Xs, W1s, W2s, W3s, bb1, bb2, bb3, dxf);
  interact_k<<<BATCH / 4, 256, 0, stream>>>(dxf, sidx, tables, Is);
  top_mlp_k<<<256, 256, 0, stream>>>(Is, WT1s, WT2s, tb1, tb2, tw3, tb3, out);
}

// Round 12
// 74.919 us; speedup vs baseline: 2.2200x; 1.1009x over previous
//
#include <hip/hip_runtime.h>

typedef unsigned short u16;
typedef _Float16 f16;
typedef __attribute__((ext_vector_type(8))) _Float16 half8;
typedef __attribute__((ext_vector_type(4))) float f32x4;
typedef __attribute__((ext_vector_type(16))) float f32x16;

#define DEV __device__ __forceinline__

static constexpr int BATCH   = 16384;
static constexpr int NTAB    = 26;
static constexpr int VOCAB   = 100000;
static constexpr int DIM     = 64;

DEV u16 f2h(float f){ union { f16 h; u16 u; } x; x.h = (f16)f; return x.u; }

// async global->LDS, 16B per lane. dst must be the wave-uniform base; HW adds lane*16.
DEV void llds16(u16* dst, const u16* src){
  __builtin_amdgcn_global_load_lds(
      (const __attribute__((address_space(1))) unsigned*)src,
      (__attribute__((address_space(3))) unsigned*)dst, 16, 0, 0);
}

DEV int crow(int reg, int half){ return (reg & 3) + 8 * (reg >> 2) + 4 * half; }

// ---------------- prep: dense conv + tiled weight transpose (single fp16) ---------
DEV void wtile(const float* __restrict__ src, u16* __restrict__ dst,
               int K, int N, int Kpad, int tile)
{
  __shared__ float ld[32][33];
  const int nt = N >> 5;
  const int k0 = (tile / nt) << 5;
  const int n0 = (tile % nt) << 5;
  const int tx = threadIdx.x & 31;
  const int ty = threadIdx.x >> 5;
  #pragma unroll
  for (int it = 0; it < 4; ++it) {
    int k = k0 + ty + 8 * it;
    ld[ty + 8 * it][tx] = (k < K) ? src[(size_t)k * N + n0 + tx] : 0.f;
  }
  __syncthreads();
  #pragma unroll
  for (int it = 0; it < 4; ++it) {
    int n  = n0 + ty + 8 * it;
    int kp = k0 + tx;
    dst[(size_t)n * Kpad + kp] = f2h(ld[tx][ty + 8 * it]);
  }
}

__global__ void prep_k(const float* __restrict__ dense, u16* __restrict__ Xs,
                       const float* __restrict__ bw1, u16* __restrict__ W1s,
                       const float* __restrict__ bw2, u16* __restrict__ W2s,
                       const float* __restrict__ bw3, u16* __restrict__ W3s,
                       const float* __restrict__ tw1, u16* __restrict__ WT1s,
                       const float* __restrict__ tw2, u16* __restrict__ WT2s)
{
  int blk = blockIdx.x;
  if (blk < 2048) {                       // dense: [B][13] -> [B][32] fp16 (0-pad)
    int i = blk * 256 + threadIdx.x;
    int b = i >> 5, k = i & 31;
    float v = (k < 13) ? dense[b * 13 + k] : 0.f;
    Xs[(size_t)b * 32 + k] = f2h(v);
  }
  else if (blk < 2064) wtile(bw1, W1s, 13, 512, 32,    blk - 2048);  // 16
  else if (blk < 2192) wtile(bw2, W2s, 512, 256, 512,  blk - 2064);  // 128
  else if (blk < 2208) wtile(bw3, W3s, 256, 64, 256,   blk - 2192);  // 16
  else if (blk < 2464) wtile(tw1, WT1s, 442, 512, 512, blk - 2208);  // 256 (K padded)
  else                 wtile(tw2, WT2s, 512, 256, 512, blk - 2464);  // 128
}

// ---------------- fused bottom MLP: X -> A1 -> A2 -> dx; 8 waves, 64 rows/block ---
__global__ __launch_bounds__(512)
void bottom_mlp_k(const u16* __restrict__ Xs, const u16* __restrict__ W1s,
                  const u16* __restrict__ W2s, const u16* __restrict__ W3s,
                  const float* __restrict__ bb1, const float* __restrict__ bb2,
                  const float* __restrict__ bb3, float* __restrict__ dxf)
{
  __shared__ alignas(16) u16 lds[67584];           // 132 KB
  u16* A1  = lds;                                  // [64][512] SW=63
  u16* S   = lds + 32768;
  u16* Xl  = S;                                    // [64][32]  SW=3
  u16* W1l = S + 2048;                             // [512][32] SW=3
  u16* W2b0 = S + 18432;                           // [256][64] SW=7
  u16* W2b1 = S;
  u16* A2  = S + 18432;                            // [64][256] SW=31
  u16* W3l = S;                                    // [64][256] SW=31

  const int tid = threadIdx.x, lane = tid & 63, wid = tid >> 6;
  int bid = blockIdx.x;
  bid = (bid & 7) * 32 + (bid >> 3);               // XCD swizzle (256 blocks)
  const int m0  = bid * 64;
  const int l31 = lane & 31, half = lane >> 5;

  auto stageW2 = [&](int t, u16* buf) {
    #pragma unroll
    for (int it = 0; it < 4; ++it) {
      int loff = (it * 512 + tid) * 16;
      int row  = loff >> 7, slot = (loff & 127) >> 4, gs = slot ^ (row & 7);
      llds16(buf + (size_t)(it * 512 + (wid << 6)) * 8,
             W2s + (size_t)row * 512 + t * 64 + gs * 8);
    }
  };

  // stage X (waves 0-3) + W1; prefetch W2(0) under G1
  if (tid < 256) {
    int loff = tid * 16, row = loff >> 6, slot = (loff & 63) >> 4, gs = slot ^ (row & 3);
    llds16(Xl + (size_t)(wid << 6) * 8, Xs + (size_t)(m0 + row) * 32 + gs * 8);
  }
  #pragma unroll
  for (int it = 0; it < 4; ++it) {
    int loff = (it * 512 + tid) * 16, row = loff >> 6, slot = (loff & 63) >> 4,
        gs = slot ^ (row & 3);
    llds16(W1l + (size_t)(it * 512 + (wid << 6)) * 8, W1s + (size_t)row * 32 + gs * 8);
  }
  stageW2(0, W2b0);
  asm volatile("s_waitcnt vmcnt(4)" ::: "memory");  // X+W1 landed; W2(0)'s 4 in flight
  __builtin_amdgcn_s_barrier();

  // G1: A1 = relu(X * W1^T + bb1), K=32; wave -> 64 cols
  f32x16 acc1[2][2] = {};
  #pragma unroll
  for (int ks = 0; ks < 2; ++ks) {
    half8 af[2], bf[2];
    #pragma unroll
    for (int mi = 0; mi < 2; ++mi) {
      int row = mi * 32 + l31, sl = (2 * ks + half) ^ (row & 3);
      af[mi] = *(const half8*)(Xl + (size_t)row * 32 + sl * 8);
    }
    #pragma unroll
    for (int ni = 0; ni < 2; ++ni) {
      int row = wid * 64 + ni * 32 + l31, sl = (2 * ks + half) ^ (row & 3);
      bf[ni] = *(const half8*)(W1l + (size_t)row * 32 + sl * 8);
    }
    #pragma unroll
    for (int mi = 0; mi < 2; ++mi)
      #pragma unroll
      for (int ni = 0; ni < 2; ++ni)
        acc1[mi][ni] = __builtin_amdgcn_mfma_f32_32x32x16_f16(af[mi], bf[ni], acc1[mi][ni], 0, 0, 0);
  }
  #pragma unroll
  for (int ni = 0; ni < 2; ++ni) {
    int col = wid * 64 + ni * 32 + l31;
    float bv = bb1[col];
    #pragma unroll
    for (int mi = 0; mi < 2; ++mi)
      #pragma unroll
      for (int reg = 0; reg < 16; ++reg) {
        int row = mi * 32 + crow(reg, half);
        float v = fmaxf(acc1[mi][ni][reg] + bv, 0.f);
        A1[(size_t)row * 512 + (((col >> 3) ^ (row & 63)) * 8) + (col & 7)] = f2h(v);
      }
  }
  __syncthreads();

  // G2: A2 = relu(A1 * W2^T + bb2), K=512, 8 steps BK=64; wave -> 32 cols
  f32x16 acc2[2] = {};
  for (int t = 0; t < 8; ++t) {
    asm volatile("s_waitcnt vmcnt(0)" ::: "memory");
    __builtin_amdgcn_s_barrier();
    if (t < 7) stageW2(t + 1, ((t + 1) & 1) ? W2b1 : W2b0);
    const u16* buf = (t & 1) ? W2b1 : W2b0;
    #pragma unroll
    for (int ks = 0; ks < 4; ++ks) {
      int s = t * 4 + ks;
      half8 af[2], bf;
      #pragma unroll
      for (int mi = 0; mi < 2; ++mi) {
        int row = mi * 32 + l31, sl = (2 * s + half) ^ (row & 63);
        af[mi] = *(const half8*)(A1 + (size_t)row * 512 + sl * 8);
      }
      {
        int row = wid * 32 + l31, sl = (2 * ks + half) ^ (row & 7);
        bf = *(const half8*)(buf + (size_t)row * 64 + sl * 8);
      }
      #pragma unroll
      for (int mi = 0; mi < 2; ++mi)
        acc2[mi] = __builtin_amdgcn_mfma_f32_32x32x16_f16(af[mi], bf, acc2[mi], 0, 0, 0);
    }
  }
  {
    int col = wid * 32 + l31;
    float bv = bb2[col];
    #pragma unroll
    for (int mi = 0; mi < 2; ++mi)
      #pragma unroll
      for (int reg = 0; reg < 16; ++reg) {
        int row = mi * 32 + crow(reg, half);
        float v = fmaxf(acc2[mi][reg] + bv, 0.f);
        A2[(size_t)row * 256 + (((col >> 3) ^ (row & 31)) * 8) + (col & 7)] = f2h(v);
      }
  }
  __syncthreads();

  // stage full W3 [64][256] (32 KB, overlays W2b1)
  #pragma unroll
  for (int it = 0; it < 4; ++it) {
    int loff = (it * 512 + tid) * 16;
    int row = loff >> 9, slot = (loff & 511) >> 4, gs = slot ^ (row & 31);
    llds16(W3l + (size_t)(it * 512 + (wid << 6)) * 8, W3s + (size_t)row * 256 + gs * 8);
  }
  asm volatile("s_waitcnt vmcnt(0)" ::: "memory");
  __builtin_amdgcn_s_barrier();

  // G3: dx[64][64] = relu(A2 * W3^T + bb3), K=256 (waves 0-3)
  if (wid < 4) {
    f32x16 acc3 = {};
    const int gm = (wid >> 1) * 32, gn = (wid & 1) * 32;
    #pragma unroll
    for (int s = 0; s < 16; ++s) {
      int rowa = gm + l31, sa = (2 * s + half) ^ (rowa & 31);
      half8 a = *(const half8*)(A2 + (size_t)rowa * 256 + sa * 8);
      int rowb = gn + l31, sb = (2 * s + half) ^ (rowb & 31);
      half8 b = *(const half8*)(W3l + (size_t)rowb * 256 + sb * 8);
      acc3 = __builtin_amdgcn_mfma_f32_32x32x16_f16(a, b, acc3, 0, 0, 0);
    }
    #pragma unroll
    for (int reg = 0; reg < 16; ++reg) {
      int col = gn + l31, row = gm + crow(reg, half);
      dxf[(size_t)(m0 + row) * 64 + col] = fmaxf(acc3[reg] + bb3[col], 0.f);
    }
  }
}

// ---------------- interaction: gather + Z = T*T^T (triu), fp16 out [B][512] -------
__global__ __launch_bounds__(256)
void interact_k(const float* __restrict__ dxf, const int* __restrict__ sidx,
                const float* __restrict__ tables, u16* __restrict__ Is)
{
  const int lane = threadIdx.x & 63;
  const int b    = blockIdx.x * 4 + (threadIdx.x >> 6);
  const float* dxrow = dxf + (size_t)b * DIM;
  u16* irow = Is + (size_t)b * 512;

  irow[lane] = f2h(dxrow[lane]);
  irow[442 + lane] = 0;                 // zero-pad 442..505
  if (lane < 6) irow[506 + lane] = 0;   // zero-pad 506..511

  const int r    = lane & 31;
  const int half = lane >> 5;
  const float* src = nullptr;
  if (r == 0)       src = dxrow;
  else if (r <= 26) {
    int id = sidx[b * NTAB + (r - 1)];
    src = tables + ((size_t)(r - 1) * VOCAB + (size_t)id) * DIM;
  }

  half8 fh[4];
  #pragma unroll
  for (int ks = 0; ks < 4; ++ks) {
    half8 h = {};
    if (src) {
      const float* p = src + ks * 16 + half * 8;
      f32x4 a = *(const f32x4*)(p);
      f32x4 c = *(const f32x4*)(p + 4);
      #pragma unroll
      for (int j = 0; j < 4; ++j) { h[j] = (f16)a[j]; h[j + 4] = (f16)c[j]; }
    }
    fh[ks] = h;
  }

  f32x16 z = {};
  #pragma unroll
  for (int ks = 0; ks < 4; ++ks)
    z = __builtin_amdgcn_mfma_f32_32x32x16_f16(fh[ks], fh[ks], z, 0, 0, 0);

  const int col = r;
  if (col < 27) {
    #pragma unroll
    for (int reg = 0; reg < 16; ++reg) {
      int rw = crow(reg, half);
      if (rw <= col) {
        int flat = rw * 27 - rw * (rw - 1) / 2 + (col - rw);
        irow[64 + flat] = f2h(z[reg]);
      }
    }
  }
}

// ---------------- fused top MLP: Is -> B1 -> y -> dot(w3) -> sigmoid -> out -------
__global__ __launch_bounds__(512)
void top_mlp_k(const u16* __restrict__ Is, const u16* __restrict__ WT1s,
               const u16* __restrict__ WT2s, const float* __restrict__ tb1,
               const float* __restrict__ tb2, const float* __restrict__ tw3,
               const float* __restrict__ tb3, float* __restrict__ out)
{
  __shared__ alignas(16) u16 lds[65536];           // 128 KB
  __shared__ float redbuf[8][64];
  u16* AB  = lds;                                  // [64][512] SW=63
  u16* Wb0 = lds + 32768;
  u16* Wb1 = lds + 49152;

  const int tid = threadIdx.x, lane = tid & 63, wid = tid >> 6;
  int bid = blockIdx.x;
  bid = (bid & 7) * 32 + (bid >> 3);               // XCD swizzle (256 blocks)
  const int m0  = bid * 64;
  const int l31 = lane & 31, half = lane >> 5;

  // W4 tile: logical [512][32] stored row-pair-packed: phys row pr=n>>1 (128 B),
  // phys slot = (4*(n&1) + logslot) ^ (pr&7). Inverse applied on global source.
  auto stageW4 = [&](int t, u16* buf) {
    #pragma unroll
    for (int it = 0; it < 4; ++it) {
      int p  = (it * 512 + tid) * 16;
      int pr = p >> 7, ps = (p & 127) >> 4;
      int un = ps ^ (pr & 7);
      int row = 2 * pr + (un >> 2), ls = un & 3;
      llds16(buf + (size_t)(it * 512 + (wid << 6)) * 8,
             WT1s + (size_t)row * 512 + t * 32 + ls * 8);
    }
  };
  auto stageW5 = [&](int t, u16* buf) {
    #pragma unroll
    for (int it = 0; it < 4; ++it) {
      int loff = (it * 512 + tid) * 16;
      int row = loff >> 7, slot = (loff & 127) >> 4, gs = slot ^ (row & 7);
      llds16(buf + (size_t)(it * 512 + (wid << 6)) * 8,
             WT2s + (size_t)row * 512 + t * 64 + gs * 8);
    }
  };

  // stage Is strip [64][512]; prefetch W4(0)
  #pragma unroll
  for (int it = 0; it < 8; ++it) {
    int loff = (it * 512 + tid) * 16;
    int row = loff >> 10, slot = (loff & 1023) >> 4, gs = slot ^ (row & 63);
    llds16(AB + (size_t)(it * 512 + (wid << 6)) * 8,
           Is + (size_t)(m0 + row) * 512 + gs * 8);
  }
  stageW4(0, Wb0);

  // G4: B1 = relu(Is * WT1^T + tb1), K=512, 16 steps BK=32; wave -> 64 cols
  f32x16 acc4[2][2] = {};
  for (int t = 0; t < 16; ++t) {
    asm volatile("s_waitcnt vmcnt(0)" ::: "memory");
    __builtin_amdgcn_s_barrier();
    if (t < 15) stageW4(t + 1, ((t + 1) & 1) ? Wb1 : Wb0);
    const u16* buf = (t & 1) ? Wb1 : Wb0;
    #pragma unroll
    for (int ks = 0; ks < 2; ++ks) {
      int s = t * 2 + ks;
      half8 af[2], bf[2];
      #pragma unroll
      for (int mi = 0; mi < 2; ++mi) {
        int row = mi * 32 + l31, sl = (2 * s + half) ^ (row & 63);
        af[mi] = *(const half8*)(AB + (size_t)row * 512 + sl * 8);
      }
      #pragma unroll
      for (int ni = 0; ni < 2; ++ni) {
        int n = wid * 64 + ni * 32 + l31;
        int pr = n >> 1;
        int ps = (4 * (n & 1) + 2 * ks + half) ^ (pr & 7);
        bf[ni] = *(const half8*)(buf + (size_t)pr * 64 + ps * 8);
      }
      #pragma unroll
      for (int mi = 0; mi < 2; ++mi)
        #pragma unroll
        for (int ni = 0; ni < 2; ++ni)
          acc4[mi][ni] = __builtin_amdgcn_mfma_f32_32x32x16_f16(af[mi], bf[ni], acc4[mi][ni], 0, 0, 0);
    }
  }
  __syncthreads();                                  // all Is reads done
  #pragma unroll
  for (int ni = 0; ni < 2; ++ni) {
    int col = wid * 64 + ni * 32 + l31;
    float bv = tb1[col];
    #pragma unroll
    for (int mi = 0; mi < 2; ++mi)
      #pragma unroll
      for (int reg = 0; reg < 16; ++reg) {
        int row = mi * 32 + crow(reg, half);
        float v = fmaxf(acc4[mi][ni][reg] + bv, 0.f);
        AB[(size_t)row * 512 + (((col >> 3) ^ (row & 63)) * 8) + (col & 7)] = f2h(v);
      }
  }
  __syncthreads();

  // G5: y = relu(B1 * WT2^T + tb2), K=512, 8 steps BK=64; wave -> 32 cols; fused dot
  stageW5(0, Wb0);
  f32x16 acc5[2] = {};
  for (int t = 0; t < 8; ++t) {
    asm volatile("s_waitcnt vmcnt(0)" ::: "memory");
    __builtin_amdgcn_s_barrier();
    if (t < 7) stageW5(t + 1, ((t + 1) & 1) ? Wb1 : Wb0);
    const u16* buf = (t & 1) ? Wb1 : Wb0;
    #pragma unroll
    for (int ks = 0; ks < 4; ++ks) {
      int s = t * 4 + ks;
      half8 af[2], bf;
      #pragma unroll
      for (int mi = 0; mi < 2; ++mi) {
        int row = mi * 32 + l31, sl = (2 * s + half) ^ (row & 63);
        af[mi] = *(const half8*)(AB + (size_t)row * 512 + sl * 8);
      }
      {
        int row = wid * 32 + l31, sl = (2 * ks + half) ^ (row & 7);
        bf = *(const half8*)(buf + (size_t)row * 64 + sl * 8);
      }
      #pragma unroll
      for (int mi = 0; mi < 2; ++mi)
        acc5[mi] = __builtin_amdgcn_mfma_f32_32x32x16_f16(af[mi], bf, acc5[mi], 0, 0, 0);
    }
  }
  // fused final layer: per-row dot of relu(y) with tw3, then sigmoid
  {
    int col = wid * 32 + l31;
    float bv = tb2[col], wv = tw3[col];
    #pragma unroll
    for (int mi = 0; mi < 2; ++mi)
      #pragma unroll
      for (int reg = 0; reg < 16; ++reg) {
        float s = fmaxf(acc5[mi][reg] + bv, 0.f) * wv;
        #pragma unroll
        for (int off = 16; off; off >>= 1) s += __shfl_xor(s, off);
        if (l31 == 0) redbuf[wid][mi * 32 + crow(reg, half)] = s;
      }
  }
  __syncthreads();
  if (tid < 64) {
    float s = tb3[0];
    #pragma unroll
    for (int w = 0; w < 8; ++w) s += redbuf[w][tid];
    out[m0 + tid] = 1.f / (1.f + expf(-s));
  }
}

// ----------------------------------------------------------------------------------
extern "C" void kernel_launch(void* const* d_in, const int* in_sizes, int n_in,
                              void* d_out, int out_size, void* d_ws, size_t ws_size,
                              hipStream_t stream)
{
  const float* dense  = (const float*)d_in[0];
  const int*   sidx   = (const int*)d_in[1];
  const float* tables = (const float*)d_in[2];
  const float* bw1 = (const float*)d_in[3];  const float* bb1 = (const float*)d_in[4];
  const float* bw2 = (const float*)d_in[5];  const float* bb2 = (const float*)d_in[6];
  const float* bw3 = (const float*)d_in[7];  const float* bb3 = (const float*)d_in[8];
  const float* tw1 = (const float*)d_in[9];  const float* tb1 = (const float*)d_in[10];
  const float* tw2 = (const float*)d_in[11]; const float* tb2 = (const float*)d_in[12];
  const float* tw3 = (const float*)d_in[13]; const float* tb3 = (const float*)d_in[14];
  float* out = (float*)d_out;

  char* ws = (char*)d_ws;
  size_t off = 0;
  auto alloc = [&](size_t bytes) { size_t o = off; off += (bytes + 1023) & ~(size_t)1023; return o; };

  u16*  Xs   = (u16*)(ws + alloc((size_t)BATCH * 32 * 2));    // [B][32]
  u16*  W1s  = (u16*)(ws + alloc((size_t)512 * 32 * 2));      // [512][32]
  u16*  W2s  = (u16*)(ws + alloc((size_t)256 * 512 * 2));     // [256][512]
  u16*  W3s  = (u16*)(ws + alloc((size_t)64 * 256 * 2));      // [64][256]
  u16*  WT1s = (u16*)(ws + alloc((size_t)512 * 512 * 2));     // [512][512] (K padded)
  u16*  WT2s = (u16*)(ws + alloc((size_t)256 * 512 * 2));     // [256][512]
  float* dxf = (float*)(ws + alloc((size_t)BATCH * 64 * 4));  // [B][64] fp32
  u16*  Is   = (u16*)(ws + alloc((size_t)BATCH * 512 * 2));   // [B][512]
  (void)ws_size; (void)n_in; (void)in_sizes; (void)out_size;

  prep_k<<<2592, 256, 0, stream>>>(dense, Xs, bw1, W1s, bw2, W2s, bw3, W3s,
                                   tw1, WT1s, tw2, WT2s);
  bottom_mlp_k<<<256, 512, 0, stream>>>(Xs, W1s, W2s, W3s, bb1, bb2, bb3, dxf);
  interact_k<<<BATCH / 4, 256, 0, stream>>>(dxf, sidx, tables, Is);
  top_mlp_k<<<256, 512, 0, stream>>>(Is, WT1s, WT2s, tb1, tb2, tw3, tb3, out);
}

// Round 13
// 68.837 us; speedup vs baseline: 2.4161x; 1.0884x over previous
//
#include <hip/hip_runtime.h>

typedef unsigned short u16;
typedef _Float16 f16;
typedef __attribute__((ext_vector_type(8))) _Float16 half8;
typedef __attribute__((ext_vector_type(4))) float f32x4;
typedef __attribute__((ext_vector_type(16))) float f32x16;

#define DEV __device__ __forceinline__

static constexpr int BATCH   = 16384;
static constexpr int NTAB    = 26;
static constexpr int VOCAB   = 100000;
static constexpr int DIM     = 64;

DEV u16 f2h(float f){ union { f16 h; u16 u; } x; x.h = (f16)f; return x.u; }

// async global->LDS, 16B per lane. dst must be the wave-uniform base; HW adds lane*16.
DEV void llds16(u16* dst, const u16* src){
  __builtin_amdgcn_global_load_lds(
      (const __attribute__((address_space(1))) unsigned*)src,
      (__attribute__((address_space(3))) unsigned*)dst, 16, 0, 0);
}

DEV int crow(int reg, int half){ return (reg & 3) + 8 * (reg >> 2) + 4 * half; }

// ---------------- prep: dense conv + tiled weight transpose (single fp16) ---------
DEV void wtile(const float* __restrict__ src, u16* __restrict__ dst,
               int K, int N, int Kpad, int tile)
{
  __shared__ float ld[32][33];
  const int nt = N >> 5;
  const int k0 = (tile / nt) << 5;
  const int n0 = (tile % nt) << 5;
  const int tx = threadIdx.x & 31;
  const int ty = threadIdx.x >> 5;
  #pragma unroll
  for (int it = 0; it < 4; ++it) {
    int k = k0 + ty + 8 * it;
    ld[ty + 8 * it][tx] = (k < K) ? src[(size_t)k * N + n0 + tx] : 0.f;
  }
  __syncthreads();
  #pragma unroll
  for (int it = 0; it < 4; ++it) {
    int n  = n0 + ty + 8 * it;
    int kp = k0 + tx;
    dst[(size_t)n * Kpad + kp] = f2h(ld[tx][ty + 8 * it]);
  }
}

__global__ void prep_k(const float* __restrict__ dense, u16* __restrict__ Xs,
                       const float* __restrict__ bw1, u16* __restrict__ W1s,
                       const float* __restrict__ bw2, u16* __restrict__ W2s,
                       const float* __restrict__ bw3, u16* __restrict__ W3s,
                       const float* __restrict__ tw1, u16* __restrict__ WT1s,
                       const float* __restrict__ tw2, u16* __restrict__ WT2s)
{
  int blk = blockIdx.x;
  if (blk < 2048) {                       // dense: [B][13] -> [B][32] fp16 (0-pad)
    int i = blk * 256 + threadIdx.x;
    int b = i >> 5, k = i & 31;
    float v = (k < 13) ? dense[b * 13 + k] : 0.f;
    Xs[(size_t)b * 32 + k] = f2h(v);
  }
  else if (blk < 2064) wtile(bw1, W1s, 13, 512, 32,    blk - 2048);  // 16
  else if (blk < 2192) wtile(bw2, W2s, 512, 256, 512,  blk - 2064);  // 128
  else if (blk < 2208) wtile(bw3, W3s, 256, 64, 256,   blk - 2192);  // 16
  else if (blk < 2464) wtile(tw1, WT1s, 442, 512, 512, blk - 2208);  // 256 (K padded)
  else                 wtile(tw2, WT2s, 512, 256, 512, blk - 2464);  // 128
}

// ---------------- mega kernel: X -> dx -> gather+Gram -> top MLP -> out -----------
// One block = 64 batch rows, 8 waves, 1 block/CU. All intermediates live in LDS:
//   R0 [0,32768)u16: A1 [64][512] SW=63, later AB (I, then B1 in-place)
//   R1 base 32768: Xl(2048) W1l(16384) | W2 dbuf | A2 | W3l | dxl f16[64][64]@34816
//                  phase2/3: Wb0@0 Wb1@16384 (32KB each)
__global__ __launch_bounds__(512)
void mega_k(const u16* __restrict__ Xs, const u16* __restrict__ W1s,
            const u16* __restrict__ W2s, const u16* __restrict__ W3s,
            const float* __restrict__ bb1, const float* __restrict__ bb2,
            const float* __restrict__ bb3, const int* __restrict__ sidx,
            const float* __restrict__ tables, const u16* __restrict__ WT1s,
            const u16* __restrict__ WT2s, const float* __restrict__ tb1,
            const float* __restrict__ tb2, const float* __restrict__ tw3,
            const float* __restrict__ tb3, float* __restrict__ out)
{
  __shared__ alignas(16) u16 lds[71680];           // 140 KB
  __shared__ float redbuf[8][64];
  u16* AB   = lds;                                 // R0: A1 / AB
  u16* R1   = lds + 32768;
  u16* Xl   = R1;                                  // [64][32]  SW=3
  u16* W1l  = R1 + 2048;                           // [512][32] SW=3
  u16* W2b0 = R1 + 18432;                          // [256][64] SW=7
  u16* W2b1 = R1;
  u16* A2   = R1 + 18432;                          // [64][256] SW=31
  u16* W3l  = R1;                                  // [64][256] SW=31
  u16* dxl  = R1 + 34816;                          // [64][64] f16, SW=7 (16B slots)
  u16* Wb0  = R1;                                  // [256][64] tiles (32 KB)
  u16* Wb1  = R1 + 16384;

  const int tid = threadIdx.x, lane = tid & 63, wid = tid >> 6;
  int bid = blockIdx.x;
  bid = (bid & 7) * 32 + (bid >> 3);               // XCD swizzle (256 blocks)
  const int m0  = bid * 64;
  const int l31 = lane & 31, half = lane >> 5;

  // ======================= phase 1: bottom MLP -> dxl =======================
  auto stageW2 = [&](int t, u16* buf) {
    #pragma unroll
    for (int it = 0; it < 4; ++it) {
      int loff = (it * 512 + tid) * 16;
      int row  = loff >> 7, slot = (loff & 127) >> 4, gs = slot ^ (row & 7);
      llds16(buf + (size_t)(it * 512 + (wid << 6)) * 8,
             W2s + (size_t)row * 512 + t * 64 + gs * 8);
    }
  };

  if (tid < 256) {
    int loff = tid * 16, row = loff >> 6, slot = (loff & 63) >> 4, gs = slot ^ (row & 3);
    llds16(Xl + (size_t)(wid << 6) * 8, Xs + (size_t)(m0 + row) * 32 + gs * 8);
  }
  #pragma unroll
  for (int it = 0; it < 4; ++it) {
    int loff = (it * 512 + tid) * 16, row = loff >> 6, slot = (loff & 63) >> 4,
        gs = slot ^ (row & 3);
    llds16(W1l + (size_t)(it * 512 + (wid << 6)) * 8, W1s + (size_t)row * 32 + gs * 8);
  }
  stageW2(0, W2b0);
  asm volatile("s_waitcnt vmcnt(4)" ::: "memory");
  __builtin_amdgcn_s_barrier();

  // G1: A1 = relu(X * W1^T + bb1), K=32; wave -> 64 cols
  {
    f32x16 acc1[2][2] = {};
    #pragma unroll
    for (int ks = 0; ks < 2; ++ks) {
      half8 af[2], bf[2];
      #pragma unroll
      for (int mi = 0; mi < 2; ++mi) {
        int row = mi * 32 + l31, sl = (2 * ks + half) ^ (row & 3);
        af[mi] = *(const half8*)(Xl + (size_t)row * 32 + sl * 8);
      }
      #pragma unroll
      for (int ni = 0; ni < 2; ++ni) {
        int row = wid * 64 + ni * 32 + l31, sl = (2 * ks + half) ^ (row & 3);
        bf[ni] = *(const half8*)(W1l + (size_t)row * 32 + sl * 8);
      }
      #pragma unroll
      for (int mi = 0; mi < 2; ++mi)
        #pragma unroll
        for (int ni = 0; ni < 2; ++ni)
          acc1[mi][ni] = __builtin_amdgcn_mfma_f32_32x32x16_f16(af[mi], bf[ni], acc1[mi][ni], 0, 0, 0);
    }
    #pragma unroll
    for (int ni = 0; ni < 2; ++ni) {
      int col = wid * 64 + ni * 32 + l31;
      float bv = bb1[col];
      #pragma unroll
      for (int mi = 0; mi < 2; ++mi)
        #pragma unroll
        for (int reg = 0; reg < 16; ++reg) {
          int row = mi * 32 + crow(reg, half);
          float v = fmaxf(acc1[mi][ni][reg] + bv, 0.f);
          AB[(size_t)row * 512 + (((col >> 3) ^ (row & 63)) * 8) + (col & 7)] = f2h(v);
        }
    }
  }
  __syncthreads();

  // G2: A2 = relu(A1 * W2^T + bb2), K=512, 8 steps BK=64; wave -> 32 cols
  {
    f32x16 acc2[2] = {};
    for (int t = 0; t < 8; ++t) {
      asm volatile("s_waitcnt vmcnt(0)" ::: "memory");
      __builtin_amdgcn_s_barrier();
      if (t < 7) stageW2(t + 1, ((t + 1) & 1) ? W2b1 : W2b0);
      const u16* buf = (t & 1) ? W2b1 : W2b0;
      #pragma unroll
      for (int ks = 0; ks < 4; ++ks) {
        int s = t * 4 + ks;
        half8 af[2], bf;
        #pragma unroll
        for (int mi = 0; mi < 2; ++mi) {
          int row = mi * 32 + l31, sl = (2 * s + half) ^ (row & 63);
          af[mi] = *(const half8*)(AB + (size_t)row * 512 + sl * 8);
        }
        {
          int row = wid * 32 + l31, sl = (2 * ks + half) ^ (row & 7);
          bf = *(const half8*)(buf + (size_t)row * 64 + sl * 8);
        }
        #pragma unroll
        for (int mi = 0; mi < 2; ++mi)
          acc2[mi] = __builtin_amdgcn_mfma_f32_32x32x16_f16(af[mi], bf, acc2[mi], 0, 0, 0);
      }
    }
    int col = wid * 32 + l31;
    float bv = bb2[col];
    #pragma unroll
    for (int mi = 0; mi < 2; ++mi)
      #pragma unroll
      for (int reg = 0; reg < 16; ++reg) {
        int row = mi * 32 + crow(reg, half);
        float v = fmaxf(acc2[mi][reg] + bv, 0.f);
        A2[(size_t)row * 256 + (((col >> 3) ^ (row & 31)) * 8) + (col & 7)] = f2h(v);
      }
  }
  __syncthreads();

  // stage full W3 [64][256] (32 KB)
  #pragma unroll
  for (int it = 0; it < 4; ++it) {
    int loff = (it * 512 + tid) * 16;
    int row = loff >> 9, slot = (loff & 511) >> 4, gs = slot ^ (row & 31);
    llds16(W3l + (size_t)(it * 512 + (wid << 6)) * 8, W3s + (size_t)row * 256 + gs * 8);
  }
  asm volatile("s_waitcnt vmcnt(0)" ::: "memory");
  __builtin_amdgcn_s_barrier();

  // G3: dx = relu(A2 * W3^T + bb3) -> dxl f16 (waves 0-3); SW=7 on 16B slots
  if (wid < 4) {
    f32x16 acc3 = {};
    const int gm = (wid >> 1) * 32, gn = (wid & 1) * 32;
    #pragma unroll
    for (int s = 0; s < 16; ++s) {
      int rowa = gm + l31, sa = (2 * s + half) ^ (rowa & 31);
      half8 a = *(const half8*)(A2 + (size_t)rowa * 256 + sa * 8);
      int rowb = gn + l31, sb = (2 * s + half) ^ (rowb & 31);
      half8 b = *(const half8*)(W3l + (size_t)rowb * 256 + sb * 8);
      acc3 = __builtin_amdgcn_mfma_f32_32x32x16_f16(a, b, acc3, 0, 0, 0);
    }
    #pragma unroll
    for (int reg = 0; reg < 16; ++reg) {
      int col = gn + l31, row = gm + crow(reg, half);
      float v = fmaxf(acc3[reg] + bb3[col], 0.f);
      dxl[(size_t)row * 64 + (((col >> 3) ^ (row & 7)) * 8) + (col & 7)] = f2h(v);
    }
  }
  __syncthreads();

  // ======================= phase 2: gather + Gram -> AB =====================
  auto stageW4 = [&](int t, u16* buf) {
    #pragma unroll
    for (int it = 0; it < 4; ++it) {
      int p  = (it * 512 + tid) * 16;
      int pr = p >> 7, ps = (p & 127) >> 4;
      int un = ps ^ (pr & 7);
      int row = 2 * pr + (un >> 2), ls = un & 3;
      llds16(buf + (size_t)(it * 512 + (wid << 6)) * 8,
             WT1s + (size_t)row * 512 + t * 32 + ls * 8);
    }
  };
  stageW4(0, Wb0);     // prefetch under the gather

  const int r = l31;
  auto gload = [&](int sr, f32x4* buf) {
    if (r >= 1 && r <= 26) {
      int id = sidx[(size_t)(m0 + sr) * NTAB + (r - 1)];
      const float* src = tables + ((size_t)(r - 1) * VOCAB + (size_t)id) * DIM;
      #pragma unroll
      for (int ks = 0; ks < 4; ++ks) {
        const float* p = src + ks * 16 + half * 8;
        buf[2 * ks]     = *(const f32x4*)(p);
        buf[2 * ks + 1] = *(const f32x4*)(p + 4);
      }
    }
  };
  auto gram = [&](int sr, const f32x4* buf) {
    // I[sr][0:64] = dx (copy f16 bits from dxl, un-swizzle read / re-swizzle write)
    {
      u16 dv = dxl[(size_t)sr * 64 + (((lane >> 3) ^ (sr & 7)) * 8) + (lane & 7)];
      AB[(size_t)sr * 512 + (((lane >> 3) ^ (sr & 63)) * 8) + (lane & 7)] = dv;
      int c = 442 + lane;
      AB[(size_t)sr * 512 + (((c >> 3) ^ (sr & 63)) * 8) + (c & 7)] = 0;
      if (lane < 6) {
        int c2 = 506 + lane;
        AB[(size_t)sr * 512 + (((c2 >> 3) ^ (sr & 63)) * 8) + (c2 & 7)] = 0;
      }
    }
    half8 fh[4];
    #pragma unroll
    for (int ks = 0; ks < 4; ++ks) {
      half8 h = {};
      if (r == 0) {
        int sl = (2 * ks + half) ^ (sr & 7);
        h = *(const half8*)(dxl + (size_t)sr * 64 + sl * 8);
      } else if (r <= 26) {
        f32x4 a = buf[2 * ks], c = buf[2 * ks + 1];
        #pragma unroll
        for (int j = 0; j < 4; ++j) { h[j] = (f16)a[j]; h[j + 4] = (f16)c[j]; }
      }
      fh[ks] = h;
    }
    f32x16 z = {};
    #pragma unroll
    for (int ks = 0; ks < 4; ++ks)
      z = __builtin_amdgcn_mfma_f32_32x32x16_f16(fh[ks], fh[ks], z, 0, 0, 0);
    if (r < 27) {
      #pragma unroll
      for (int reg = 0; reg < 16; ++reg) {
        int rw = crow(reg, half);
        if (rw <= r) {
          int c = 64 + rw * 27 - rw * (rw - 1) / 2 + (r - rw);
          AB[(size_t)sr * 512 + (((c >> 3) ^ (sr & 63)) * 8) + (c & 7)] = f2h(z[reg]);
        }
      }
    }
  };

  {
    f32x4 bufA[8], bufB[8];
    gload(wid * 8 + 0, bufA);
    #pragma unroll
    for (int jj = 0; jj < 8; jj += 2) {
      if (jj + 1 < 8) gload(wid * 8 + jj + 1, bufB);
      gram(wid * 8 + jj, bufA);
      if (jj + 2 < 8) gload(wid * 8 + jj + 2, bufA);
      if (jj + 1 < 8) gram(wid * 8 + jj + 1, bufB);
    }
  }
  __syncthreads();

  // ======================= phase 3: top MLP -> out ==========================
  auto stageW5 = [&](int t, u16* buf) {
    #pragma unroll
    for (int it = 0; it < 4; ++it) {
      int loff = (it * 512 + tid) * 16;
      int row = loff >> 7, slot = (loff & 127) >> 4, gs = slot ^ (row & 7);
      llds16(buf + (size_t)(it * 512 + (wid << 6)) * 8,
             WT2s + (size_t)row * 512 + t * 64 + gs * 8);
    }
  };

  // G4: B1 = relu(I * WT1^T + tb1), K=512, 16 steps BK=32; wave -> 64 cols
  {
    f32x16 acc4[2][2] = {};
    for (int t = 0; t < 16; ++t) {
      asm volatile("s_waitcnt vmcnt(0)" ::: "memory");
      __builtin_amdgcn_s_barrier();
      if (t < 15) stageW4(t + 1, ((t + 1) & 1) ? Wb1 : Wb0);
      const u16* buf = (t & 1) ? Wb1 : Wb0;
      #pragma unroll
      for (int ks = 0; ks < 2; ++ks) {
        int s = t * 2 + ks;
        half8 af[2], bf[2];
        #pragma unroll
        for (int mi = 0; mi < 2; ++mi) {
          int row = mi * 32 + l31, sl = (2 * s + half) ^ (row & 63);
          af[mi] = *(const half8*)(AB + (size_t)row * 512 + sl * 8);
        }
        #pragma unroll
        for (int ni = 0; ni < 2; ++ni) {
          int n = wid * 64 + ni * 32 + l31;
          int pr = n >> 1;
          int ps = (4 * (n & 1) + 2 * ks + half) ^ (pr & 7);
          bf[ni] = *(const half8*)(buf + (size_t)pr * 64 + ps * 8);
        }
        #pragma unroll
        for (int mi = 0; mi < 2; ++mi)
          #pragma unroll
          for (int ni = 0; ni < 2; ++ni)
            acc4[mi][ni] = __builtin_amdgcn_mfma_f32_32x32x16_f16(af[mi], bf[ni], acc4[mi][ni], 0, 0, 0);
      }
    }
    __syncthreads();
    #pragma unroll
    for (int ni = 0; ni < 2; ++ni) {
      int col = wid * 64 + ni * 32 + l31;
      float bv = tb1[col];
      #pragma unroll
      for (int mi = 0; mi < 2; ++mi)
        #pragma unroll
        for (int reg = 0; reg < 16; ++reg) {
          int row = mi * 32 + crow(reg, half);
          float v = fmaxf(acc4[mi][ni][reg] + bv, 0.f);
          AB[(size_t)row * 512 + (((col >> 3) ^ (row & 63)) * 8) + (col & 7)] = f2h(v);
        }
    }
  }
  __syncthreads();

  // G5: y = relu(B1 * WT2^T + tb2), K=512, 8 steps BK=64; fused final dot
  {
    stageW5(0, Wb0);
    f32x16 acc5[2] = {};
    for (int t = 0; t < 8; ++t) {
      asm volatile("s_waitcnt vmcnt(0)" ::: "memory");
      __builtin_amdgcn_s_barrier();
      if (t < 7) stageW5(t + 1, ((t + 1) & 1) ? Wb1 : Wb0);
      const u16* buf = (t & 1) ? Wb1 : Wb0;
      #pragma unroll
      for (int ks = 0; ks < 4; ++ks) {
        int s = t * 4 + ks;
        half8 af[2], bf;
        #pragma unroll
        for (int mi = 0; mi < 2; ++mi) {
          int row = mi * 32 + l31, sl = (2 * s + half) ^ (row & 63);
          af[mi] = *(const half8*)(AB + (size_t)row * 512 + sl * 8);
        }
        {
          int row = wid * 32 + l31, sl = (2 * ks + half) ^ (row & 7);
          bf = *(const half8*)(buf + (size_t)row * 64 + sl * 8);
        }
        #pragma unroll
        for (int mi = 0; mi < 2; ++mi)
          acc5[mi] = __builtin_amdgcn_mfma_f32_32x32x16_f16(af[mi], bf, acc5[mi], 0, 0, 0);
      }
    }
    int col = wid * 32 + l31;
    float bv = tb2[col], wv = tw3[col];
    #pragma unroll
    for (int mi = 0; mi < 2; ++mi)
      #pragma unroll
      for (int reg = 0; reg < 16; ++reg) {
        float s = fmaxf(acc5[mi][reg] + bv, 0.f) * wv;
        #pragma unroll
        for (int off = 16; off; off >>= 1) s += __shfl_xor(s, off);
        if (l31 == 0) redbuf[wid][mi * 32 + crow(reg, half)] = s;
      }
  }
  __syncthreads();
  if (tid < 64) {
    float s = tb3[0];
    #pragma unroll
    for (int w = 0; w < 8; ++w) s += redbuf[w][tid];
    out[m0 + tid] = 1.f / (1.f + expf(-s));
  }
}

// ----------------------------------------------------------------------------------
extern "C" void kernel_launch(void* const* d_in, const int* in_sizes, int n_in,
                              void* d_out, int out_size, void* d_ws, size_t ws_size,
                              hipStream_t stream)
{
  const float* dense  = (const float*)d_in[0];
  const int*   sidx   = (const int*)d_in[1];
  const float* tables = (const float*)d_in[2];
  const float* bw1 = (const float*)d_in[3];  const float* bb1 = (const float*)d_in[4];
  const float* bw2 = (const float*)d_in[5];  const float* bb2 = (const float*)d_in[6];
  const float* bw3 = (const float*)d_in[7];  const float* bb3 = (const float*)d_in[8];
  const float* tw1 = (const float*)d_in[9];  const float* tb1 = (const float*)d_in[10];
  const float* tw2 = (const float*)d_in[11]; const float* tb2 = (const float*)d_in[12];
  const float* tw3 = (const float*)d_in[13]; const float* tb3 = (const float*)d_in[14];
  float* out = (float*)d_out;

  char* ws = (char*)d_ws;
  size_t off = 0;
  auto alloc = [&](size_t bytes) { size_t o = off; off += (bytes + 1023) & ~(size_t)1023; return o; };

  u16*  Xs   = (u16*)(ws + alloc((size_t)BATCH * 32 * 2));    // [B][32]
  u16*  W1s  = (u16*)(ws + alloc((size_t)512 * 32 * 2));      // [512][32]
  u16*  W2s  = (u16*)(ws + alloc((size_t)256 * 512 * 2));     // [256][512]
  u16*  W3s  = (u16*)(ws + alloc((size_t)64 * 256 * 2));      // [64][256]
  u16*  WT1s = (u16*)(ws + alloc((size_t)512 * 512 * 2));     // [512][512] (K padded)
  u16*  WT2s = (u16*)(ws + alloc((size_t)256 * 512 * 2));     // [256][512]
  (void)ws_size; (void)n_in; (void)in_sizes; (void)out_size;

  prep_k<<<2592, 256, 0, stream>>>(dense, Xs, bw1, W1s, bw2, W2s, bw3, W3s,
                                   tw1, WT1s, tw2, WT2s);
  mega_k<<<256, 512, 0, stream>>>(Xs, W1s, W2s, W3s, bb1, bb2, bb3, sidx, tables,
                                  WT1s, WT2s, tb1, tb2, tw3, tb3, out);
}